// Round 2
// baseline (1173.266 us; speedup 1.0000x reference)
//
#include <hip/hip_runtime.h>
#include <hip/hip_bf16.h>

typedef __attribute__((ext_vector_type(4))) float f32x4;
typedef __attribute__((ext_vector_type(8))) short bf16x8;

#define B_ROWS 16384
#define IN_DIM 768
#define H1 512
#define H2 256
#define NC 50
#define NC_PAD 64
#define NE 8
#define RH1 256
#define RH2 128

static __device__ __forceinline__ f32x4 mfma16(bf16x8 a, bf16x8 b, f32x4 c) {
    return __builtin_amdgcn_mfma_f32_16x16x32_bf16(a, b, c, 0, 0, 0);
}

// ---------------- ternarize: W (E, rows, cols) f32 -> ternary {-1,0,1} bf16 (E, rows_pad, cols)
__global__ __launch_bounds__(512) void ternarize_kernel(
    const float* __restrict__ W, __hip_bfloat16* __restrict__ Wq,
    float* __restrict__ scales, int rows, int cols, int rows_pad)
{
    const int e = blockIdx.x;
    const int n = rows * cols;
    const float* We = W + (size_t)e * n;
    __hip_bfloat16* Wo = Wq + (size_t)e * rows_pad * cols;

    float s = 0.f;
    for (int i = threadIdx.x; i < n; i += 512) s += fabsf(We[i]);
    __shared__ float red[9];
    const int lane = threadIdx.x & 63, wave = threadIdx.x >> 6;
    #pragma unroll
    for (int o = 32; o; o >>= 1) s += __shfl_down(s, o);
    if (lane == 0) red[wave] = s;
    __syncthreads();
    if (threadIdx.x == 0) {
        float t = 0.f;
        #pragma unroll
        for (int i = 0; i < 8; ++i) t += red[i];
        scales[e] = t / (float)n;
    }
    const int ntot = rows_pad * cols;
    for (int i = threadIdx.x; i < ntot; i += 512) {
        float q = 0.f;
        if (i < n) {
            float w = We[i];
            q = (fabsf(w) > 0.05f) ? (w > 0.f ? 1.f : -1.f) : 0.f;
        }
        Wo[i] = __float2bfloat16(q);
    }
}

// ---------------- split f32 -> (hi, lo) bf16 pair
__global__ __launch_bounds__(256) void decomp_kernel(
    const float* __restrict__ in, ushort* __restrict__ hi, ushort* __restrict__ lo, int n4)
{
    for (int i = blockIdx.x * 256 + threadIdx.x; i < n4; i += gridDim.x * 256) {
        float4 v = ((const float4*)in)[i];
        ushort4 hh, ll;
        float vv[4] = {v.x, v.y, v.z, v.w};
        ushort ho[4], lo4[4];
        #pragma unroll
        for (int j = 0; j < 4; ++j) {
            __hip_bfloat16 h = __float2bfloat16(vv[j]);
            float hf = __bfloat162float(h);
            __hip_bfloat16 l = __float2bfloat16(vv[j] - hf);
            ho[j] = *(ushort*)&h; lo4[j] = *(ushort*)&l;
        }
        hh.x = ho[0]; hh.y = ho[1]; hh.z = ho[2]; hh.w = ho[3];
        ll.x = lo4[0]; ll.y = lo4[1]; ll.z = lo4[2]; ll.w = lo4[3];
        ((ushort4*)hi)[i] = hh; ((ushort4*)lo)[i] = ll;
    }
}

// ---------------- split-bf16 "f32-accurate" GEMM: C = relu(A@B^T + bias)
// acc = Ah*Bh + Ah*Bl + Al*Bh  (error ~2^-16 rel). LDS-free, 4 waves, 64x64 tile.
// EPI==1: write bf16 hi/lo pair. EPI==2: write f32.
template<int EPI>
__global__ __launch_bounds__(256) void gemm3t_kernel(
    const ushort* __restrict__ Ah, const ushort* __restrict__ Al,
    const ushort* __restrict__ Bh, const ushort* __restrict__ Bl,
    const float* __restrict__ bias,
    ushort* __restrict__ Oh, ushort* __restrict__ Ol, float* __restrict__ Of,
    int M, int N, int K)
{
    const int wave = threadIdx.x >> 6, lane = threadIdx.x & 63;
    const int lm = lane & 15, lk = lane >> 4;
    const int m0 = blockIdx.x * 64 + wave * 16;
    const int n0 = blockIdx.y * 64;
    const ushort* arh = Ah + (size_t)(m0 + lm) * K;
    const ushort* arl = Al + (size_t)(m0 + lm) * K;
    f32x4 acc[4] = {};
    for (int kk = 0; kk < K; kk += 32) {
        bf16x8 ah = *(const bf16x8*)(arh + kk + lk * 8);
        bf16x8 al = *(const bf16x8*)(arl + kk + lk * 8);
        #pragma unroll
        for (int n = 0; n < 4; ++n) {
            size_t boff = (size_t)(n0 + n * 16 + lm) * K + kk + lk * 8;
            bf16x8 bh = *(const bf16x8*)(Bh + boff);
            bf16x8 bl = *(const bf16x8*)(Bl + boff);
            acc[n] = mfma16(ah, bh, acc[n]);
            acc[n] = mfma16(ah, bl, acc[n]);
            acc[n] = mfma16(al, bh, acc[n]);
        }
    }
    #pragma unroll
    for (int n = 0; n < 4; ++n) {
        int col = n0 + n * 16 + lm;
        float bv = bias[col];
        #pragma unroll
        for (int r = 0; r < 4; ++r) {
            int row = m0 + lk * 4 + r;
            float v = acc[n][r] + bv;
            v = v > 0.f ? v : 0.f;
            if (EPI == 1) {
                __hip_bfloat16 h = __float2bfloat16(v);
                float hf = __bfloat162float(h);
                __hip_bfloat16 l = __float2bfloat16(v - hf);
                Oh[(size_t)row * N + col] = *(ushort*)&h;
                Ol[(size_t)row * N + col] = *(ushort*)&l;
            } else {
                Of[(size_t)row * N + col] = v;
            }
        }
    }
}

// ---------------- router head: logits(8) from h2(128) f32, softmax, top-2, gate,
// and append (row<<1)|slot to per-expert dispatch lists.
__global__ __launch_bounds__(256) void router_head_kernel(
    const float* __restrict__ h2, const float* __restrict__ rW3,
    const float* __restrict__ rb3, float* __restrict__ router_p,
    float* __restrict__ gate, float* __restrict__ lb_out,
    int* __restrict__ counts, int* __restrict__ ent)
{
    const int wave = threadIdx.x >> 6;
    const int lane = threadIdx.x & 63;
    const int b = blockIdx.x * 4 + wave;
    const int o = lane >> 3;
    const int kq = lane & 7;
    const float* h = h2 + (size_t)b * RH2;
    const float* w = rW3 + o * RH2;
    float s = 0.f;
    #pragma unroll
    for (int k = 0; k < 16; ++k) s += h[kq * 16 + k] * w[kq * 16 + k];
    s += __shfl_xor(s, 1);
    s += __shfl_xor(s, 2);
    s += __shfl_xor(s, 4);
    float logit = s + rb3[o];
    float l[8];
    #pragma unroll
    for (int i = 0; i < 8; ++i) l[i] = __shfl(logit, i * 8);
    float m = l[0];
    #pragma unroll
    for (int i = 1; i < 8; ++i) m = fmaxf(m, l[i]);
    float p[8]; float sum = 0.f;
    #pragma unroll
    for (int i = 0; i < 8; ++i) { p[i] = expf(l[i] - m); sum += p[i]; }
    float inv = 1.f / sum;
    #pragma unroll
    for (int i = 0; i < 8; ++i) p[i] *= inv;
    int i1 = 0; float v1 = p[0];
    #pragma unroll
    for (int i = 1; i < 8; ++i) if (p[i] > v1) { v1 = p[i]; i1 = i; }
    int i2 = -1; float v2 = -1.f;
    #pragma unroll
    for (int i = 0; i < 8; ++i) if (i != i1 && p[i] > v2) { v2 = p[i]; i2 = i; }
    if (lane < 8) {
        router_p[(size_t)b * 8 + lane] = p[lane];
        float g = (lane == i1) ? v1 * 0.5f : ((lane == i2) ? v2 * 0.5f : 0.f);
        gate[(size_t)b * 8 + lane] = g;
    }
    if (lane == 0) {
        int pos1 = atomicAdd(&counts[i1], 1);
        ent[i1 * B_ROWS + pos1] = (b << 1);        // slot 0 (top-1)
        int pos2 = atomicAdd(&counts[i2], 1);
        ent[i2 * B_ROWS + pos2] = (b << 1) | 1;    // slot 1 (top-2)
    }
    if (blockIdx.x == 0 && threadIdx.x == 0) lb_out[0] = 0.f;
}

// ---------------- sparse fused expert kernel: block = (expert e, tile t) of 32 assigned rows.
__global__ __launch_bounds__(512) void expert_fused_kernel(
    const ushort* __restrict__ xh,           // (16384,768) bf16 hi of x
    const __hip_bfloat16* __restrict__ W1q,
    const __hip_bfloat16* __restrict__ W2q,
    const __hip_bfloat16* __restrict__ W3q,
    const float* __restrict__ s1, const float* __restrict__ s2, const float* __restrict__ s3,
    const float* __restrict__ eb1, const float* __restrict__ eb2, const float* __restrict__ eb3,
    const float* __restrict__ gate,
    const int* __restrict__ counts, const int* __restrict__ ent,
    float* __restrict__ S0, float* __restrict__ S1)   // (16384,64) gated contributions
{
    const int e = blockIdx.y, t = blockIdx.x;
    const int cnt = counts[e];
    if (t * 32 >= cnt) return;

    __shared__ __align__(16) __hip_bfloat16 Xb[32][776];
    __shared__ __align__(16) __hip_bfloat16 A1s[32][520];
    __shared__ __align__(16) __hip_bfloat16 A2s[32][264];
    __shared__ int rowL[32];
    __shared__ int slotL[32];
    __shared__ float gL[32];

    const int tid = threadIdx.x;
    const int wave = tid >> 6;
    const int lane = tid & 63;
    const int lm = lane & 15;
    const int lk = lane >> 4;

    if (tid < 32) {
        int idx = t * 32 + tid;
        if (idx < cnt) {
            int entv = ent[e * B_ROWS + idx];
            int r = entv >> 1;
            rowL[tid] = r;
            slotL[tid] = entv & 1;
            gL[tid] = gate[(size_t)r * NE + e];
        } else {
            rowL[tid] = -1; slotL[tid] = 0; gL[tid] = 0.f;
        }
    }
    __syncthreads();

    // stage 32 gathered rows of xh (bf16) into LDS
    for (int i = tid; i < 32 * (IN_DIM / 8); i += 512) {
        int row = i / (IN_DIM / 8), c8 = (i % (IN_DIM / 8)) * 8;
        int R = rowL[row]; if (R < 0) R = 0;
        *(bf16x8*)&Xb[row][c8] = *(const bf16x8*)(xh + (size_t)R * IN_DIM + c8);
    }
    __syncthreads();

    // ---- layer 1: Xb(32x768) @ W1q_e(512x768)^T -> A1s, scale+bias+relu
    {
        const __hip_bfloat16* W = W1q + (size_t)e * H1 * IN_DIM;
        const float* bias = eb1 + e * H1;
        const float sc = s1[e];
        f32x4 acc[2][4] = {};
        bf16x8 bn[4];
        #pragma unroll
        for (int n = 0; n < 4; ++n)
            bn[n] = *(const bf16x8*)&W[(size_t)((wave * 4 + n) * 16 + lm) * IN_DIM + lk * 8];
        for (int kk = 0; kk < IN_DIM; kk += 32) {
            bf16x8 bc[4];
            #pragma unroll
            for (int n = 0; n < 4; ++n) bc[n] = bn[n];
            if (kk + 32 < IN_DIM) {
                #pragma unroll
                for (int n = 0; n < 4; ++n)
                    bn[n] = *(const bf16x8*)&W[(size_t)((wave * 4 + n) * 16 + lm) * IN_DIM + kk + 32 + lk * 8];
            }
            bf16x8 a0 = *(const bf16x8*)&Xb[lm][kk + lk * 8];
            bf16x8 a1 = *(const bf16x8*)&Xb[16 + lm][kk + lk * 8];
            #pragma unroll
            for (int n = 0; n < 4; ++n) {
                acc[0][n] = mfma16(a0, bc[n], acc[0][n]);
                acc[1][n] = mfma16(a1, bc[n], acc[1][n]);
            }
        }
        #pragma unroll
        for (int n = 0; n < 4; ++n) {
            int ncol = (wave * 4 + n) * 16 + lm;
            float bv = bias[ncol];
            #pragma unroll
            for (int m = 0; m < 2; ++m)
                #pragma unroll
                for (int r = 0; r < 4; ++r) {
                    float v = fmaf(acc[m][n][r], sc, bv);
                    v = v > 0.f ? v : 0.f;
                    A1s[m * 16 + lk * 4 + r][ncol] = __float2bfloat16(v);
                }
        }
    }
    __syncthreads();

    // ---- layer 2: A1s(32x512) @ W2q_e(256x512)^T -> A2s
    {
        const __hip_bfloat16* W = W2q + (size_t)e * H2 * H1;
        const float* bias = eb2 + e * H2;
        const float sc = s2[e];
        f32x4 acc[2][2] = {};
        bf16x8 bn[2];
        #pragma unroll
        for (int n = 0; n < 2; ++n)
            bn[n] = *(const bf16x8*)&W[(size_t)((wave * 2 + n) * 16 + lm) * H1 + lk * 8];
        for (int kk = 0; kk < H1; kk += 32) {
            bf16x8 bc[2];
            #pragma unroll
            for (int n = 0; n < 2; ++n) bc[n] = bn[n];
            if (kk + 32 < H1) {
                #pragma unroll
                for (int n = 0; n < 2; ++n)
                    bn[n] = *(const bf16x8*)&W[(size_t)((wave * 2 + n) * 16 + lm) * H1 + kk + 32 + lk * 8];
            }
            bf16x8 a0 = *(const bf16x8*)&A1s[lm][kk + lk * 8];
            bf16x8 a1 = *(const bf16x8*)&A1s[16 + lm][kk + lk * 8];
            #pragma unroll
            for (int n = 0; n < 2; ++n) {
                acc[0][n] = mfma16(a0, bc[n], acc[0][n]);
                acc[1][n] = mfma16(a1, bc[n], acc[1][n]);
            }
        }
        #pragma unroll
        for (int n = 0; n < 2; ++n) {
            int ncol = (wave * 2 + n) * 16 + lm;
            float bv = bias[ncol];
            #pragma unroll
            for (int m = 0; m < 2; ++m)
                #pragma unroll
                for (int r = 0; r < 4; ++r) {
                    float v = fmaf(acc[m][n][r], sc, bv);
                    v = v > 0.f ? v : 0.f;
                    A2s[m * 16 + lk * 4 + r][ncol] = __float2bfloat16(v);
                }
        }
    }
    __syncthreads();

    // ---- layer 3: A2s(32x256) @ W3q_e(64x256)^T -> gated write to slot buffer
    {
        const __hip_bfloat16* W = W3q + (size_t)e * NC_PAD * H2;
        const float* bias = eb3 + e * NC;
        const float sc = s3[e];
        const int mt = wave & 1, nt = wave >> 1;
        f32x4 acc = {};
        for (int kk = 0; kk < H2; kk += 32) {
            bf16x8 a = *(const bf16x8*)&A2s[mt * 16 + lm][kk + lk * 8];
            bf16x8 b = *(const bf16x8*)&W[(size_t)(nt * 16 + lm) * H2 + kk + lk * 8];
            acc = mfma16(a, b, acc);
        }
        int col = nt * 16 + lm;
        if (col < NC) {
            float bv = bias[col];
            #pragma unroll
            for (int r = 0; r < 4; ++r) {
                int row = mt * 16 + lk * 4 + r;
                int R = rowL[row];
                if (R >= 0) {
                    float v = gL[row] * fmaf(acc[r], sc, bv);
                    float* Sb = slotL[row] ? S1 : S0;
                    Sb[(size_t)R * 64 + col] = v;
                }
            }
        }
    }
}

// ---------------- combine: out[row] = S0[row] + S1[row]
__global__ __launch_bounds__(256) void combine_kernel(
    const float* __restrict__ S0, const float* __restrict__ S1, float* __restrict__ out)
{
    int i = blockIdx.x * 256 + threadIdx.x;
    if (i < B_ROWS * NC) {
        int row = i / NC, col = i % NC;
        out[i] = S0[(size_t)row * 64 + col] + S1[(size_t)row * 64 + col];
    }
}

extern "C" void kernel_launch(void* const* d_in, const int* in_sizes, int n_in,
                              void* d_out, int out_size, void* d_ws, size_t ws_size,
                              hipStream_t stream) {
    const float* x   = (const float*)d_in[0];
    const float* rW1 = (const float*)d_in[1];
    const float* rb1 = (const float*)d_in[2];
    const float* rW2 = (const float*)d_in[3];
    const float* rb2 = (const float*)d_in[4];
    const float* rW3 = (const float*)d_in[5];
    const float* rb3 = (const float*)d_in[6];
    const float* eW1 = (const float*)d_in[7];
    const float* eb1 = (const float*)d_in[8];
    const float* eW2 = (const float*)d_in[9];
    const float* eb2 = (const float*)d_in[10];
    const float* eW3 = (const float*)d_in[11];
    const float* eb3 = (const float*)d_in[12];

    float* out_main = (float*)d_out;                       // (16384,50)
    float* router_p = out_main + (size_t)B_ROWS * NC;      // (16384,8)
    float* lb_out   = router_p + (size_t)B_ROWS * NE;      // scalar

    char* ws = (char*)d_ws;
    size_t off = 0;
    __hip_bfloat16* W1q = (__hip_bfloat16*)(ws + off); off += (size_t)NE * H1 * IN_DIM * 2;
    __hip_bfloat16* W2q = (__hip_bfloat16*)(ws + off); off += (size_t)NE * H2 * H1 * 2;
    __hip_bfloat16* W3q = (__hip_bfloat16*)(ws + off); off += (size_t)NE * NC_PAD * H2 * 2;
    ushort* xh  = (ushort*)(ws + off); off += (size_t)B_ROWS * IN_DIM * 2;
    ushort* xl  = (ushort*)(ws + off);                         // aliased: h2 (f32) lives here after gemm1
    float*  h2  = (float*)xl;
    off += (size_t)B_ROWS * IN_DIM * 2;
    ushort* h1h = (ushort*)(ws + off);                         // aliased: S0 after gemm2
    float*  S0  = (float*)h1h;
    off += (size_t)B_ROWS * RH1 * 2;
    ushort* h1l = (ushort*)(ws + off);                         // aliased: S1 after gemm2
    float*  S1  = (float*)h1l;
    off += (size_t)B_ROWS * RH1 * 2;
    ushort* w1h = (ushort*)(ws + off); off += (size_t)RH1 * IN_DIM * 2;
    ushort* w1l = (ushort*)(ws + off); off += (size_t)RH1 * IN_DIM * 2;
    ushort* w2h = (ushort*)(ws + off); off += (size_t)RH2 * RH1 * 2;
    ushort* w2l = (ushort*)(ws + off); off += (size_t)RH2 * RH1 * 2;
    float* gate = (float*)(ws + off); off += (size_t)B_ROWS * NE * 4;
    int*   ent  = (int*)(ws + off);   off += (size_t)NE * B_ROWS * 4;
    int* counts = (int*)(ws + off);   off += 256;
    float* s1   = (float*)(ws + off); off += 256;
    float* s2   = (float*)(ws + off); off += 256;
    float* s3   = (float*)(ws + off); off += 256;

    // 1) ternarize expert weights; decompose x and router weights into bf16 hi/lo
    ternarize_kernel<<<NE, 512, 0, stream>>>(eW1, W1q, s1, H1, IN_DIM, H1);
    ternarize_kernel<<<NE, 512, 0, stream>>>(eW2, W2q, s2, H2, H1, H2);
    ternarize_kernel<<<NE, 512, 0, stream>>>(eW3, W3q, s3, NC, H2, NC_PAD);
    decomp_kernel<<<2048, 256, 0, stream>>>(x, xh, xl, B_ROWS * IN_DIM / 4);
    decomp_kernel<<<192, 256, 0, stream>>>(rW1, w1h, w1l, RH1 * IN_DIM / 4);
    decomp_kernel<<<32, 256, 0, stream>>>(rW2, w2h, w2l, RH2 * RH1 / 4);

    // 2) router MLP via split-bf16 MFMA (f32-class accuracy)
    gemm3t_kernel<1><<<dim3(B_ROWS / 64, RH1 / 64), 256, 0, stream>>>(
        xh, xl, w1h, w1l, rb1, h1h, h1l, nullptr, B_ROWS, RH1, IN_DIM);
    gemm3t_kernel<2><<<dim3(B_ROWS / 64, RH2 / 64), 256, 0, stream>>>(
        h1h, h1l, w2h, w2l, rb2, nullptr, nullptr, h2, B_ROWS, RH2, RH1);

    hipMemsetAsync(counts, 0, 32, stream);
    router_head_kernel<<<B_ROWS / 4, 256, 0, stream>>>(
        h2, rW3, rb3, router_p, gate, lb_out, counts, ent);

    // 3) sparse fused experts (top-2 only) + combine
    expert_fused_kernel<<<dim3(B_ROWS / 32, NE), 512, 0, stream>>>(
        xh, W1q, W2q, W3q, s1, s2, s3, eb1, eb2, eb3, gate, counts, ent, S0, S1);
    combine_kernel<<<(B_ROWS * NC + 255) / 256, 256, 0, stream>>>(S0, S1, out_main);
}

// Round 3
// 370.529 us; speedup vs baseline: 3.1665x; 3.1665x over previous
//
#include <hip/hip_runtime.h>
#include <hip/hip_bf16.h>

typedef __attribute__((ext_vector_type(4))) float f32x4;
typedef __attribute__((ext_vector_type(8))) short bf16x8;

#define B_ROWS 16384
#define IN_DIM 768
#define H1 512
#define H2 256
#define NC 50
#define NC_PAD 64
#define NE 8
#define RH1 256
#define RH2 128
#define NBLK_SUM 32

static __device__ __forceinline__ f32x4 mfma16(bf16x8 a, bf16x8 b, f32x4 c) {
    return __builtin_amdgcn_mfma_f32_16x16x32_bf16(a, b, c, 0, 0, 0);
}

// ---------------- abs-sum partial reduce: grid (NBLK_SUM, NE), 256 thr
__global__ __launch_bounds__(256) void absum_kernel(
    const float* __restrict__ W, float* __restrict__ partial, int n)
{
    const int e = blockIdx.y;
    const float4* We = (const float4*)(W + (size_t)e * n);
    const int n4 = n >> 2;
    float s = 0.f;
    for (int i = blockIdx.x * 256 + threadIdx.x; i < n4; i += NBLK_SUM * 256) {
        float4 v = We[i];
        s += fabsf(v.x) + fabsf(v.y) + fabsf(v.z) + fabsf(v.w);
    }
    const int lane = threadIdx.x & 63, wave = threadIdx.x >> 6;
    #pragma unroll
    for (int o = 32; o; o >>= 1) s += __shfl_down(s, o);
    __shared__ float red[4];
    if (lane == 0) red[wave] = s;
    __syncthreads();
    if (threadIdx.x == 0)
        partial[e * NBLK_SUM + blockIdx.x] = red[0] + red[1] + red[2] + red[3];
}

// ---------------- finalize scales: 1 block
__global__ __launch_bounds__(64) void finalize_scales_kernel(
    const float* __restrict__ p1, const float* __restrict__ p2, const float* __restrict__ p3,
    float* __restrict__ s1, float* __restrict__ s2, float* __restrict__ s3)
{
    int t = threadIdx.x;
    if (t < 8) {
        float a = 0.f;
        for (int i = 0; i < NBLK_SUM; ++i) a += p1[t * NBLK_SUM + i];
        s1[t] = a / (float)(H1 * IN_DIM);
    } else if (t < 16) {
        int e = t - 8; float a = 0.f;
        for (int i = 0; i < NBLK_SUM; ++i) a += p2[e * NBLK_SUM + i];
        s2[e] = a / (float)(H2 * H1);
    } else if (t < 24) {
        int e = t - 16; float a = 0.f;
        for (int i = 0; i < NBLK_SUM; ++i) a += p3[e * NBLK_SUM + i];
        s3[e] = a / (float)(NC * H2);
    }
}

// ---------------- quantize: grid (ceil(ntot/1024), NE), 256 thr, 4 elems/thr
__global__ __launch_bounds__(256) void quant_kernel(
    const float* __restrict__ W, __hip_bfloat16* __restrict__ Wq, int n, int ntot)
{
    const int e = blockIdx.y;
    const float* We = W + (size_t)e * n;
    __hip_bfloat16* Wo = Wq + (size_t)e * ntot;
    int i4 = (blockIdx.x * 256 + threadIdx.x) * 4;
    if (i4 >= ntot) return;
    ushort o[4];
    #pragma unroll
    for (int j = 0; j < 4; ++j) {
        int i = i4 + j;
        float q = 0.f;
        if (i < n) {
            float w = We[i];
            q = (fabsf(w) > 0.05f) ? (w > 0.f ? 1.f : -1.f) : 0.f;
        }
        __hip_bfloat16 h = __float2bfloat16(q);
        o[j] = *(ushort*)&h;
    }
    *(ushort4*)&Wo[i4] = make_ushort4(o[0], o[1], o[2], o[3]);
}

// ---------------- split f32 -> (hi, lo) bf16 pair
__global__ __launch_bounds__(256) void decomp_kernel(
    const float* __restrict__ in, ushort* __restrict__ hi, ushort* __restrict__ lo, int n4)
{
    for (int i = blockIdx.x * 256 + threadIdx.x; i < n4; i += gridDim.x * 256) {
        float4 v = ((const float4*)in)[i];
        float vv[4] = {v.x, v.y, v.z, v.w};
        ushort ho[4], lo4[4];
        #pragma unroll
        for (int j = 0; j < 4; ++j) {
            __hip_bfloat16 h = __float2bfloat16(vv[j]);
            float hf = __bfloat162float(h);
            __hip_bfloat16 l = __float2bfloat16(vv[j] - hf);
            ho[j] = *(ushort*)&h; lo4[j] = *(ushort*)&l;
        }
        ((ushort4*)hi)[i] = make_ushort4(ho[0], ho[1], ho[2], ho[3]);
        ((ushort4*)lo)[i] = make_ushort4(lo4[0], lo4[1], lo4[2], lo4[3]);
    }
}

// ---------------- split-bf16 "f32-accurate" GEMM: C = relu(A@B^T + bias)
template<int EPI>
__global__ __launch_bounds__(256) void gemm3t_kernel(
    const ushort* __restrict__ Ah, const ushort* __restrict__ Al,
    const ushort* __restrict__ Bh, const ushort* __restrict__ Bl,
    const float* __restrict__ bias,
    ushort* __restrict__ Oh, ushort* __restrict__ Ol, float* __restrict__ Of,
    int M, int N, int K)
{
    const int wave = threadIdx.x >> 6, lane = threadIdx.x & 63;
    const int lm = lane & 15, lk = lane >> 4;
    const int m0 = blockIdx.x * 64 + wave * 16;
    const int n0 = blockIdx.y * 64;
    const ushort* arh = Ah + (size_t)(m0 + lm) * K;
    const ushort* arl = Al + (size_t)(m0 + lm) * K;
    f32x4 acc[4] = {};
    for (int kk = 0; kk < K; kk += 32) {
        bf16x8 ah = *(const bf16x8*)(arh + kk + lk * 8);
        bf16x8 al = *(const bf16x8*)(arl + kk + lk * 8);
        #pragma unroll
        for (int n = 0; n < 4; ++n) {
            size_t boff = (size_t)(n0 + n * 16 + lm) * K + kk + lk * 8;
            bf16x8 bh = *(const bf16x8*)(Bh + boff);
            bf16x8 bl = *(const bf16x8*)(Bl + boff);
            acc[n] = mfma16(ah, bh, acc[n]);
            acc[n] = mfma16(ah, bl, acc[n]);
            acc[n] = mfma16(al, bh, acc[n]);
        }
    }
    #pragma unroll
    for (int n = 0; n < 4; ++n) {
        int col = n0 + n * 16 + lm;
        float bv = bias[col];
        #pragma unroll
        for (int r = 0; r < 4; ++r) {
            int row = m0 + lk * 4 + r;
            float v = acc[n][r] + bv;
            v = v > 0.f ? v : 0.f;
            if (EPI == 1) {
                __hip_bfloat16 h = __float2bfloat16(v);
                float hf = __bfloat162float(h);
                __hip_bfloat16 l = __float2bfloat16(v - hf);
                Oh[(size_t)row * N + col] = *(ushort*)&h;
                Ol[(size_t)row * N + col] = *(ushort*)&l;
            } else {
                Of[(size_t)row * N + col] = v;
            }
        }
    }
}

// ---------------- router head: softmax + top-2; NO global atomics.
__global__ __launch_bounds__(256) void router_head_kernel(
    const float* __restrict__ h2, const float* __restrict__ rW3,
    const float* __restrict__ rb3, float* __restrict__ router_p,
    float* __restrict__ gate, float* __restrict__ lb_out,
    int* __restrict__ t2)
{
    const int wave = threadIdx.x >> 6;
    const int lane = threadIdx.x & 63;
    const int b = blockIdx.x * 4 + wave;
    const int o = lane >> 3;
    const int kq = lane & 7;
    const float* h = h2 + (size_t)b * RH2;
    const float* w = rW3 + o * RH2;
    float s = 0.f;
    #pragma unroll
    for (int k = 0; k < 16; ++k) s += h[kq * 16 + k] * w[kq * 16 + k];
    s += __shfl_xor(s, 1);
    s += __shfl_xor(s, 2);
    s += __shfl_xor(s, 4);
    float logit = s + rb3[o];
    float l[8];
    #pragma unroll
    for (int i = 0; i < 8; ++i) l[i] = __shfl(logit, i * 8);
    float m = l[0];
    #pragma unroll
    for (int i = 1; i < 8; ++i) m = fmaxf(m, l[i]);
    float p[8]; float sum = 0.f;
    #pragma unroll
    for (int i = 0; i < 8; ++i) { p[i] = expf(l[i] - m); sum += p[i]; }
    float inv = 1.f / sum;
    #pragma unroll
    for (int i = 0; i < 8; ++i) p[i] *= inv;
    int i1 = 0; float v1 = p[0];
    #pragma unroll
    for (int i = 1; i < 8; ++i) if (p[i] > v1) { v1 = p[i]; i1 = i; }
    int i2 = -1; float v2 = -1.f;
    #pragma unroll
    for (int i = 0; i < 8; ++i) if (i != i1 && p[i] > v2) { v2 = p[i]; i2 = i; }
    if (lane < 8) {
        router_p[(size_t)b * 8 + lane] = p[lane];
        float g = (lane == i1) ? v1 * 0.5f : ((lane == i2) ? v2 * 0.5f : 0.f);
        gate[(size_t)b * 8 + lane] = g;
    }
    if (lane == 0) t2[b] = i1 | (i2 << 8);
    if (blockIdx.x == 0 && threadIdx.x == 0) lb_out[0] = 0.f;
}

// ---------------- build dispatch lists: block-aggregated atomics (64 blocks x 256 rows)
__global__ __launch_bounds__(256) void build_lists_kernel(
    const int* __restrict__ t2, int* __restrict__ counts, int* __restrict__ ent)
{
    __shared__ int hist[8], base[8];
    const int r = blockIdx.x * 256 + threadIdx.x;
    if (threadIdx.x < 8) hist[threadIdx.x] = 0;
    __syncthreads();
    const int v = t2[r];
    const int i1 = v & 255, i2 = v >> 8;
    const int rk1 = atomicAdd(&hist[i1], 1);
    const int rk2 = atomicAdd(&hist[i2], 1);
    __syncthreads();
    if (threadIdx.x < 8) base[threadIdx.x] = atomicAdd(&counts[threadIdx.x], hist[threadIdx.x]);
    __syncthreads();
    ent[i1 * B_ROWS + base[i1] + rk1] = (r << 1);
    ent[i2 * B_ROWS + base[i2] + rk2] = (r << 1) | 1;
}

// ---------------- sparse fused expert kernel: block = (expert e, tile t) of 32 assigned rows.
__global__ __launch_bounds__(512) void expert_fused_kernel(
    const ushort* __restrict__ xh,
    const __hip_bfloat16* __restrict__ W1q,
    const __hip_bfloat16* __restrict__ W2q,
    const __hip_bfloat16* __restrict__ W3q,
    const float* __restrict__ s1, const float* __restrict__ s2, const float* __restrict__ s3,
    const float* __restrict__ eb1, const float* __restrict__ eb2, const float* __restrict__ eb3,
    const float* __restrict__ gate,
    const int* __restrict__ counts, const int* __restrict__ ent,
    float* __restrict__ S0, float* __restrict__ S1)
{
    const int e = blockIdx.y, t = blockIdx.x;
    const int cnt = counts[e];
    if (t * 32 >= cnt) return;

    __shared__ __align__(16) __hip_bfloat16 Xb[32][776];
    __shared__ __align__(16) __hip_bfloat16 A1s[32][520];
    __shared__ __align__(16) __hip_bfloat16 A2s[32][264];
    __shared__ int rowL[32];
    __shared__ int slotL[32];
    __shared__ float gL[32];

    const int tid = threadIdx.x;
    const int wave = tid >> 6;
    const int lane = tid & 63;
    const int lm = lane & 15;
    const int lk = lane >> 4;

    if (tid < 32) {
        int idx = t * 32 + tid;
        if (idx < cnt) {
            int entv = ent[e * B_ROWS + idx];
            int r = entv >> 1;
            rowL[tid] = r;
            slotL[tid] = entv & 1;
            gL[tid] = gate[(size_t)r * NE + e];
        } else {
            rowL[tid] = -1; slotL[tid] = 0; gL[tid] = 0.f;
        }
    }
    __syncthreads();

    for (int i = tid; i < 32 * (IN_DIM / 8); i += 512) {
        int row = i / (IN_DIM / 8), c8 = (i % (IN_DIM / 8)) * 8;
        int R = rowL[row]; if (R < 0) R = 0;
        *(bf16x8*)&Xb[row][c8] = *(const bf16x8*)(xh + (size_t)R * IN_DIM + c8);
    }
    __syncthreads();

    // ---- layer 1
    {
        const __hip_bfloat16* W = W1q + (size_t)e * H1 * IN_DIM;
        const float* bias = eb1 + e * H1;
        const float sc = s1[e];
        f32x4 acc[2][4] = {};
        bf16x8 bn[4];
        #pragma unroll
        for (int n = 0; n < 4; ++n)
            bn[n] = *(const bf16x8*)&W[(size_t)((wave * 4 + n) * 16 + lm) * IN_DIM + lk * 8];
        for (int kk = 0; kk < IN_DIM; kk += 32) {
            bf16x8 bc[4];
            #pragma unroll
            for (int n = 0; n < 4; ++n) bc[n] = bn[n];
            if (kk + 32 < IN_DIM) {
                #pragma unroll
                for (int n = 0; n < 4; ++n)
                    bn[n] = *(const bf16x8*)&W[(size_t)((wave * 4 + n) * 16 + lm) * IN_DIM + kk + 32 + lk * 8];
            }
            bf16x8 a0 = *(const bf16x8*)&Xb[lm][kk + lk * 8];
            bf16x8 a1 = *(const bf16x8*)&Xb[16 + lm][kk + lk * 8];
            #pragma unroll
            for (int n = 0; n < 4; ++n) {
                acc[0][n] = mfma16(a0, bc[n], acc[0][n]);
                acc[1][n] = mfma16(a1, bc[n], acc[1][n]);
            }
        }
        #pragma unroll
        for (int n = 0; n < 4; ++n) {
            int ncol = (wave * 4 + n) * 16 + lm;
            float bv = bias[ncol];
            #pragma unroll
            for (int m = 0; m < 2; ++m)
                #pragma unroll
                for (int r = 0; r < 4; ++r) {
                    float v = fmaf(acc[m][n][r], sc, bv);
                    v = v > 0.f ? v : 0.f;
                    A1s[m * 16 + lk * 4 + r][ncol] = __float2bfloat16(v);
                }
        }
    }
    __syncthreads();

    // ---- layer 2
    {
        const __hip_bfloat16* W = W2q + (size_t)e * H2 * H1;
        const float* bias = eb2 + e * H2;
        const float sc = s2[e];
        f32x4 acc[2][2] = {};
        bf16x8 bn[2];
        #pragma unroll
        for (int n = 0; n < 2; ++n)
            bn[n] = *(const bf16x8*)&W[(size_t)((wave * 2 + n) * 16 + lm) * H1 + lk * 8];
        for (int kk = 0; kk < H1; kk += 32) {
            bf16x8 bc[2];
            #pragma unroll
            for (int n = 0; n < 2; ++n) bc[n] = bn[n];
            if (kk + 32 < H1) {
                #pragma unroll
                for (int n = 0; n < 2; ++n)
                    bn[n] = *(const bf16x8*)&W[(size_t)((wave * 2 + n) * 16 + lm) * H1 + kk + 32 + lk * 8];
            }
            bf16x8 a0 = *(const bf16x8*)&A1s[lm][kk + lk * 8];
            bf16x8 a1 = *(const bf16x8*)&A1s[16 + lm][kk + lk * 8];
            #pragma unroll
            for (int n = 0; n < 2; ++n) {
                acc[0][n] = mfma16(a0, bc[n], acc[0][n]);
                acc[1][n] = mfma16(a1, bc[n], acc[1][n]);
            }
        }
        #pragma unroll
        for (int n = 0; n < 2; ++n) {
            int ncol = (wave * 2 + n) * 16 + lm;
            float bv = bias[ncol];
            #pragma unroll
            for (int m = 0; m < 2; ++m)
                #pragma unroll
                for (int r = 0; r < 4; ++r) {
                    float v = fmaf(acc[m][n][r], sc, bv);
                    v = v > 0.f ? v : 0.f;
                    A2s[m * 16 + lk * 4 + r][ncol] = __float2bfloat16(v);
                }
        }
    }
    __syncthreads();

    // ---- layer 3
    {
        const __hip_bfloat16* W = W3q + (size_t)e * NC_PAD * H2;
        const float* bias = eb3 + e * NC;
        const float sc = s3[e];
        const int mt = wave & 1, nt = wave >> 1;
        f32x4 acc = {};
        for (int kk = 0; kk < H2; kk += 32) {
            bf16x8 a = *(const bf16x8*)&A2s[mt * 16 + lm][kk + lk * 8];
            bf16x8 b = *(const bf16x8*)&W[(size_t)(nt * 16 + lm) * H2 + kk + lk * 8];
            acc = mfma16(a, b, acc);
        }
        int col = nt * 16 + lm;
        if (col < NC) {
            float bv = bias[col];
            #pragma unroll
            for (int r = 0; r < 4; ++r) {
                int row = mt * 16 + lk * 4 + r;
                int R = rowL[row];
                if (R >= 0) {
                    float v = gL[row] * fmaf(acc[r], sc, bv);
                    float* Sb = slotL[row] ? S1 : S0;
                    Sb[(size_t)R * 64 + col] = v;
                }
            }
        }
    }
}

// ---------------- combine
__global__ __launch_bounds__(256) void combine_kernel(
    const float* __restrict__ S0, const float* __restrict__ S1, float* __restrict__ out)
{
    int i = blockIdx.x * 256 + threadIdx.x;
    if (i < B_ROWS * NC) {
        int row = i / NC, col = i % NC;
        out[i] = S0[(size_t)row * 64 + col] + S1[(size_t)row * 64 + col];
    }
}

extern "C" void kernel_launch(void* const* d_in, const int* in_sizes, int n_in,
                              void* d_out, int out_size, void* d_ws, size_t ws_size,
                              hipStream_t stream) {
    const float* x   = (const float*)d_in[0];
    const float* rW1 = (const float*)d_in[1];
    const float* rb1 = (const float*)d_in[2];
    const float* rW2 = (const float*)d_in[3];
    const float* rb2 = (const float*)d_in[4];
    const float* rW3 = (const float*)d_in[5];
    const float* rb3 = (const float*)d_in[6];
    const float* eW1 = (const float*)d_in[7];
    const float* eb1 = (const float*)d_in[8];
    const float* eW2 = (const float*)d_in[9];
    const float* eb2 = (const float*)d_in[10];
    const float* eW3 = (const float*)d_in[11];
    const float* eb3 = (const float*)d_in[12];

    float* out_main = (float*)d_out;
    float* router_p = out_main + (size_t)B_ROWS * NC;
    float* lb_out   = router_p + (size_t)B_ROWS * NE;

    char* ws = (char*)d_ws;
    size_t off = 0;
    __hip_bfloat16* W1q = (__hip_bfloat16*)(ws + off); off += (size_t)NE * H1 * IN_DIM * 2;
    __hip_bfloat16* W2q = (__hip_bfloat16*)(ws + off); off += (size_t)NE * H2 * H1 * 2;
    __hip_bfloat16* W3q = (__hip_bfloat16*)(ws + off); off += (size_t)NE * NC_PAD * H2 * 2;
    ushort* xh  = (ushort*)(ws + off); off += (size_t)B_ROWS * IN_DIM * 2;
    ushort* xl  = (ushort*)(ws + off);
    float*  h2  = (float*)xl;
    off += (size_t)B_ROWS * IN_DIM * 2;
    ushort* h1h = (ushort*)(ws + off);
    float*  S0  = (float*)h1h;
    off += (size_t)B_ROWS * RH1 * 2;
    ushort* h1l = (ushort*)(ws + off);
    float*  S1  = (float*)h1l;
    off += (size_t)B_ROWS * RH1 * 2;
    // S0/S1 are (16384,64) f32 = 4 MB each; h1h/h1l are only 8 MB total region start;
    // give S0/S1 their own space to be safe:
    float* S0r = (float*)(ws + off); off += (size_t)B_ROWS * 64 * 4;
    float* S1r = (float*)(ws + off); off += (size_t)B_ROWS * 64 * 4;
    S0 = S0r; S1 = S1r;
    ushort* w1h = (ushort*)(ws + off); off += (size_t)RH1 * IN_DIM * 2;
    ushort* w1l = (ushort*)(ws + off); off += (size_t)RH1 * IN_DIM * 2;
    ushort* w2h = (ushort*)(ws + off); off += (size_t)RH2 * RH1 * 2;
    ushort* w2l = (ushort*)(ws + off); off += (size_t)RH2 * RH1 * 2;
    float* gate = (float*)(ws + off); off += (size_t)B_ROWS * NE * 4;
    int*   ent  = (int*)(ws + off);   off += (size_t)NE * B_ROWS * 4;
    int*   t2   = (int*)(ws + off);   off += (size_t)B_ROWS * 4;
    int* counts = (int*)(ws + off);   off += 256;
    float* s1   = (float*)(ws + off); off += 256;
    float* s2   = (float*)(ws + off); off += 256;
    float* s3   = (float*)(ws + off); off += 256;
    float* p1   = (float*)(ws + off); off += NE * NBLK_SUM * 4;
    float* p2   = (float*)(ws + off); off += NE * NBLK_SUM * 4;
    float* p3   = (float*)(ws + off); off += NE * NBLK_SUM * 4;

    // 1) ternarize (parallel): partial reduce -> scales -> quantize
    absum_kernel<<<dim3(NBLK_SUM, NE), 256, 0, stream>>>(eW1, p1, H1 * IN_DIM);
    absum_kernel<<<dim3(NBLK_SUM, NE), 256, 0, stream>>>(eW2, p2, H2 * H1);
    absum_kernel<<<dim3(NBLK_SUM, NE), 256, 0, stream>>>(eW3, p3, NC * H2);
    finalize_scales_kernel<<<1, 64, 0, stream>>>(p1, p2, p3, s1, s2, s3);
    quant_kernel<<<dim3(H1 * IN_DIM / 1024, NE), 256, 0, stream>>>(eW1, W1q, H1 * IN_DIM, H1 * IN_DIM);
    quant_kernel<<<dim3(H2 * H1 / 1024, NE), 256, 0, stream>>>(eW2, W2q, H2 * H1, H2 * H1);
    quant_kernel<<<dim3(NC_PAD * H2 / 1024, NE), 256, 0, stream>>>(eW3, W3q, NC * H2, NC_PAD * H2);

    // decompose x and router weights into bf16 hi/lo
    decomp_kernel<<<2048, 256, 0, stream>>>(x, xh, xl, B_ROWS * IN_DIM / 4);
    decomp_kernel<<<192, 256, 0, stream>>>(rW1, w1h, w1l, RH1 * IN_DIM / 4);
    decomp_kernel<<<32, 256, 0, stream>>>(rW2, w2h, w2l, RH2 * RH1 / 4);

    // 2) router MLP via split-bf16 MFMA
    gemm3t_kernel<1><<<dim3(B_ROWS / 64, RH1 / 64), 256, 0, stream>>>(
        xh, xl, w1h, w1l, rb1, h1h, h1l, nullptr, B_ROWS, RH1, IN_DIM);
    gemm3t_kernel<2><<<dim3(B_ROWS / 64, RH2 / 64), 256, 0, stream>>>(
        h1h, h1l, w2h, w2l, rb2, nullptr, nullptr, h2, B_ROWS, RH2, RH1);

    router_head_kernel<<<B_ROWS / 4, 256, 0, stream>>>(
        h2, rW3, rb3, router_p, gate, lb_out, t2);
    hipMemsetAsync(counts, 0, 32, stream);
    build_lists_kernel<<<B_ROWS / 256, 256, 0, stream>>>(t2, counts, ent);

    // 3) sparse fused experts (top-2 only) + combine
    expert_fused_kernel<<<dim3(B_ROWS / 32, NE), 512, 0, stream>>>(
        xh, W1q, W2q, W3q, s1, s2, s3, eb1, eb2, eb3, gate, counts, ent, S0, S1);
    combine_kernel<<<(B_ROWS * NC + 255) / 256, 256, 0, stream>>>(S0, S1, out_main);
}

// Round 4
// 363.740 us; speedup vs baseline: 3.2256x; 1.0187x over previous
//
#include <hip/hip_runtime.h>
#include <hip/hip_bf16.h>

typedef __attribute__((ext_vector_type(4))) float f32x4;
typedef __attribute__((ext_vector_type(8))) short bf16x8;

#define B_ROWS 16384
#define IN_DIM 768
#define H1 512
#define H2 256
#define NC 50
#define NC_PAD 64
#define NE 8
#define RH1 256
#define RH2 128
#define NBLK_SUM 32

static __device__ __forceinline__ f32x4 mfma16(bf16x8 a, bf16x8 b, f32x4 c) {
    return __builtin_amdgcn_mfma_f32_16x16x32_bf16(a, b, c, 0, 0, 0);
}

// ---------------- merged abs-sum partial reduce: grid (NBLK_SUM, 24)
__global__ __launch_bounds__(256) void absum_all_kernel(
    const float* __restrict__ eW1, const float* __restrict__ eW2, const float* __restrict__ eW3,
    float* __restrict__ p1, float* __restrict__ p2, float* __restrict__ p3)
{
    const int mat = blockIdx.y >> 3, e = blockIdx.y & 7;
    const float* W; float* P; int n;
    if (mat == 0)      { W = eW1; P = p1; n = H1 * IN_DIM; }
    else if (mat == 1) { W = eW2; P = p2; n = H2 * H1; }
    else               { W = eW3; P = p3; n = NC * H2; }
    const float4* We = (const float4*)(W + (size_t)e * n);
    const int n4 = n >> 2;
    float s = 0.f;
    for (int i = blockIdx.x * 256 + threadIdx.x; i < n4; i += NBLK_SUM * 256) {
        float4 v = We[i];
        s += fabsf(v.x) + fabsf(v.y) + fabsf(v.z) + fabsf(v.w);
    }
    const int lane = threadIdx.x & 63, wave = threadIdx.x >> 6;
    #pragma unroll
    for (int o = 32; o; o >>= 1) s += __shfl_down(s, o);
    __shared__ float red[4];
    if (lane == 0) red[wave] = s;
    __syncthreads();
    if (threadIdx.x == 0)
        P[e * NBLK_SUM + blockIdx.x] = red[0] + red[1] + red[2] + red[3];
}

// ---------------- finalize scales + zero dispatch counts
__global__ __launch_bounds__(64) void finalize_scales_kernel(
    const float* __restrict__ p1, const float* __restrict__ p2, const float* __restrict__ p3,
    float* __restrict__ s1, float* __restrict__ s2, float* __restrict__ s3,
    int* __restrict__ counts)
{
    int t = threadIdx.x;
    if (t < 8) {
        float a = 0.f;
        for (int i = 0; i < NBLK_SUM; ++i) a += p1[t * NBLK_SUM + i];
        s1[t] = a / (float)(H1 * IN_DIM);
    } else if (t < 16) {
        int e = t - 8; float a = 0.f;
        for (int i = 0; i < NBLK_SUM; ++i) a += p2[e * NBLK_SUM + i];
        s2[e] = a / (float)(H2 * H1);
    } else if (t < 24) {
        int e = t - 16; float a = 0.f;
        for (int i = 0; i < NBLK_SUM; ++i) a += p3[e * NBLK_SUM + i];
        s3[e] = a / (float)(NC * H2);
    } else if (t < 32) {
        counts[t - 24] = 0;
    }
}

// ---------------- merged quantize: grid (384, 24)
__global__ __launch_bounds__(256) void quant_all_kernel(
    const float* __restrict__ eW1, const float* __restrict__ eW2, const float* __restrict__ eW3,
    __hip_bfloat16* __restrict__ W1q, __hip_bfloat16* __restrict__ W2q, __hip_bfloat16* __restrict__ W3q)
{
    const int mat = blockIdx.y >> 3, e = blockIdx.y & 7;
    const float* W; __hip_bfloat16* Q; int n, ntot;
    if (mat == 0)      { W = eW1; Q = W1q; n = H1 * IN_DIM; ntot = n; }
    else if (mat == 1) { W = eW2; Q = W2q; n = H2 * H1;     ntot = n; }
    else               { W = eW3; Q = W3q; n = NC * H2;     ntot = NC_PAD * H2; }
    int i4 = (blockIdx.x * 256 + threadIdx.x) * 4;
    if (i4 >= ntot) return;
    const float* We = W + (size_t)e * n;
    __hip_bfloat16* Wo = Q + (size_t)e * ntot;
    ushort o[4];
    #pragma unroll
    for (int j = 0; j < 4; ++j) {
        int i = i4 + j;
        float q = 0.f;
        if (i < n) {
            float w = We[i];
            q = (fabsf(w) > 0.05f) ? (w > 0.f ? 1.f : -1.f) : 0.f;
        }
        __hip_bfloat16 h = __float2bfloat16(q);
        o[j] = *(ushort*)&h;
    }
    *(ushort4*)&Wo[i4] = make_ushort4(o[0], o[1], o[2], o[3]);
}

// ---------------- merged hi/lo decomposition: x (3072 blocks), rW1 (48), rW2 (8)
static __device__ __forceinline__ void decomp4(
    const float4* __restrict__ in, ushort4* __restrict__ hi, ushort4* __restrict__ lo, int i)
{
    float4 v = in[i];
    float vv[4] = {v.x, v.y, v.z, v.w};
    ushort ho[4], lo4[4];
    #pragma unroll
    for (int j = 0; j < 4; ++j) {
        __hip_bfloat16 h = __float2bfloat16(vv[j]);
        float hf = __bfloat162float(h);
        __hip_bfloat16 l = __float2bfloat16(vv[j] - hf);
        ho[j] = *(ushort*)&h; lo4[j] = *(ushort*)&l;
    }
    hi[i] = make_ushort4(ho[0], ho[1], ho[2], ho[3]);
    lo[i] = make_ushort4(lo4[0], lo4[1], lo4[2], lo4[3]);
}

__global__ __launch_bounds__(256) void decomp_all_kernel(
    const float* __restrict__ x, ushort* __restrict__ xh, ushort* __restrict__ xl,
    const float* __restrict__ rW1, ushort* __restrict__ w1h, ushort* __restrict__ w1l,
    const float* __restrict__ rW2, ushort* __restrict__ w2h, ushort* __restrict__ w2l)
{
    const int bx = blockIdx.x;
    const float4* in; ushort4* hi; ushort4* lo; int base;
    if (bx < 3072)      { in = (const float4*)x;   hi = (ushort4*)xh;  lo = (ushort4*)xl;  base = bx * 1024; }
    else if (bx < 3120) { in = (const float4*)rW1; hi = (ushort4*)w1h; lo = (ushort4*)w1l; base = (bx - 3072) * 1024; }
    else                { in = (const float4*)rW2; hi = (ushort4*)w2h; lo = (ushort4*)w2l; base = (bx - 3120) * 1024; }
    #pragma unroll
    for (int j = 0; j < 4; ++j)
        decomp4(in, hi, lo, base + j * 256 + threadIdx.x);
}

// ---------------- fully fused router: x -> h1 -> h2 -> logits/softmax/top2.
// 32 rows per block, 8 waves. Split-bf16 3-term MFMA for f32-class accuracy.
__global__ __launch_bounds__(512, 4) void router_fused_kernel(
    const ushort* __restrict__ xh, const ushort* __restrict__ xl,
    const ushort* __restrict__ w1h, const ushort* __restrict__ w1l, const float* __restrict__ rb1,
    const ushort* __restrict__ w2h, const ushort* __restrict__ w2l, const float* __restrict__ rb2,
    const float* __restrict__ rW3, const float* __restrict__ rb3,
    float* __restrict__ router_p, float* __restrict__ gate,
    float* __restrict__ lb_out, int* __restrict__ t2)
{
    __shared__ __align__(16) ushort h1hs[32][264];
    __shared__ __align__(16) ushort h1ls[32][264];
    __shared__ __align__(16) float h2s[32][132];

    const int tid = threadIdx.x, wave = tid >> 6, lane = tid & 63;
    const int lm = lane & 15, lk = lane >> 4;
    const int r0 = blockIdx.x * 32;

    // ---- layer 1: (32 x 768) @ rW1^T(256x768) -> h1 (32x256), wave covers cols wave*32..+31
    {
        const ushort* a0h = xh + (size_t)(r0 + lm) * IN_DIM + lk * 8;
        const ushort* a0l = xl + (size_t)(r0 + lm) * IN_DIM + lk * 8;
        const ushort* a1h = xh + (size_t)(r0 + 16 + lm) * IN_DIM + lk * 8;
        const ushort* a1l = xl + (size_t)(r0 + 16 + lm) * IN_DIM + lk * 8;
        const ushort* b0h = w1h + (size_t)(wave * 32 + lm) * IN_DIM + lk * 8;
        const ushort* b0l = w1l + (size_t)(wave * 32 + lm) * IN_DIM + lk * 8;
        const ushort* b1h = w1h + (size_t)(wave * 32 + 16 + lm) * IN_DIM + lk * 8;
        const ushort* b1l = w1l + (size_t)(wave * 32 + 16 + lm) * IN_DIM + lk * 8;
        f32x4 acc[2][2] = {};
        for (int kk = 0; kk < IN_DIM; kk += 32) {
            bf16x8 ah0 = *(const bf16x8*)(a0h + kk), al0 = *(const bf16x8*)(a0l + kk);
            bf16x8 ah1 = *(const bf16x8*)(a1h + kk), al1 = *(const bf16x8*)(a1l + kk);
            bf16x8 bh0 = *(const bf16x8*)(b0h + kk), bl0 = *(const bf16x8*)(b0l + kk);
            bf16x8 bh1 = *(const bf16x8*)(b1h + kk), bl1 = *(const bf16x8*)(b1l + kk);
            acc[0][0] = mfma16(ah0, bh0, acc[0][0]);
            acc[0][0] = mfma16(ah0, bl0, acc[0][0]);
            acc[0][0] = mfma16(al0, bh0, acc[0][0]);
            acc[0][1] = mfma16(ah0, bh1, acc[0][1]);
            acc[0][1] = mfma16(ah0, bl1, acc[0][1]);
            acc[0][1] = mfma16(al0, bh1, acc[0][1]);
            acc[1][0] = mfma16(ah1, bh0, acc[1][0]);
            acc[1][0] = mfma16(ah1, bl0, acc[1][0]);
            acc[1][0] = mfma16(al1, bh0, acc[1][0]);
            acc[1][1] = mfma16(ah1, bh1, acc[1][1]);
            acc[1][1] = mfma16(ah1, bl1, acc[1][1]);
            acc[1][1] = mfma16(al1, bh1, acc[1][1]);
        }
        #pragma unroll
        for (int n = 0; n < 2; ++n) {
            int col = wave * 32 + n * 16 + lm;
            float bv = rb1[col];
            #pragma unroll
            for (int m = 0; m < 2; ++m)
                #pragma unroll
                for (int r = 0; r < 4; ++r) {
                    float v = acc[m][n][r] + bv;
                    v = v > 0.f ? v : 0.f;
                    __hip_bfloat16 h = __float2bfloat16(v);
                    float hf = __bfloat162float(h);
                    __hip_bfloat16 l = __float2bfloat16(v - hf);
                    int row = m * 16 + lk * 4 + r;
                    h1hs[row][col] = *(ushort*)&h;
                    h1ls[row][col] = *(ushort*)&l;
                }
        }
    }
    __syncthreads();

    // ---- layer 2: (32 x 256) @ rW2^T(128x256) -> h2 (32x128), wave covers col wave*16+lm
    {
        const ushort* b2h = w2h + (size_t)(wave * 16 + lm) * RH1 + lk * 8;
        const ushort* b2l = w2l + (size_t)(wave * 16 + lm) * RH1 + lk * 8;
        f32x4 acc2[2] = {};
        for (int kk = 0; kk < RH1; kk += 32) {
            bf16x8 ah0 = *(const bf16x8*)&h1hs[lm][kk + lk * 8];
            bf16x8 al0 = *(const bf16x8*)&h1ls[lm][kk + lk * 8];
            bf16x8 ah1 = *(const bf16x8*)&h1hs[16 + lm][kk + lk * 8];
            bf16x8 al1 = *(const bf16x8*)&h1ls[16 + lm][kk + lk * 8];
            bf16x8 bh = *(const bf16x8*)(b2h + kk);
            bf16x8 bl = *(const bf16x8*)(b2l + kk);
            acc2[0] = mfma16(ah0, bh, acc2[0]);
            acc2[0] = mfma16(ah0, bl, acc2[0]);
            acc2[0] = mfma16(al0, bh, acc2[0]);
            acc2[1] = mfma16(ah1, bh, acc2[1]);
            acc2[1] = mfma16(ah1, bl, acc2[1]);
            acc2[1] = mfma16(al1, bh, acc2[1]);
        }
        int col2 = wave * 16 + lm;
        float bv = rb2[col2];
        #pragma unroll
        for (int m = 0; m < 2; ++m)
            #pragma unroll
            for (int r = 0; r < 4; ++r) {
                float v = acc2[m][r] + bv;
                h2s[m * 16 + lk * 4 + r][col2] = v > 0.f ? v : 0.f;
            }
    }
    __syncthreads();

    // ---- head: wave handles rows wave*4..+3; per row: 8 lanes per expert
    const int o = lane >> 3, kq = lane & 7;
    #pragma unroll
    for (int i = 0; i < 4; ++i) {
        int rloc = wave * 4 + i;
        int b = r0 + rloc;
        float s = 0.f;
        #pragma unroll
        for (int q = 0; q < 4; ++q) {
            float4 hv = *(const float4*)&h2s[rloc][kq * 16 + q * 4];
            float4 wv = *(const float4*)&rW3[o * RH2 + kq * 16 + q * 4];
            s += hv.x * wv.x + hv.y * wv.y + hv.z * wv.z + hv.w * wv.w;
        }
        s += __shfl_xor(s, 1);
        s += __shfl_xor(s, 2);
        s += __shfl_xor(s, 4);
        float logit = s + rb3[o];
        float l[8];
        #pragma unroll
        for (int j = 0; j < 8; ++j) l[j] = __shfl(logit, j * 8);
        float m = l[0];
        #pragma unroll
        for (int j = 1; j < 8; ++j) m = fmaxf(m, l[j]);
        float p[8]; float sum = 0.f;
        #pragma unroll
        for (int j = 0; j < 8; ++j) { p[j] = expf(l[j] - m); sum += p[j]; }
        float inv = 1.f / sum;
        #pragma unroll
        for (int j = 0; j < 8; ++j) p[j] *= inv;
        int i1 = 0; float v1 = p[0];
        #pragma unroll
        for (int j = 1; j < 8; ++j) if (p[j] > v1) { v1 = p[j]; i1 = j; }
        int i2 = -1; float v2 = -1.f;
        #pragma unroll
        for (int j = 0; j < 8; ++j) if (j != i1 && p[j] > v2) { v2 = p[j]; i2 = j; }
        if (lane < 8) {
            router_p[(size_t)b * 8 + lane] = p[lane];
            float g = (lane == i1) ? v1 * 0.5f : ((lane == i2) ? v2 * 0.5f : 0.f);
            gate[(size_t)b * 8 + lane] = g;
        }
        if (lane == 0) t2[b] = i1 | (i2 << 8);
    }
    if (blockIdx.x == 0 && tid == 0) lb_out[0] = 0.f;
}

// ---------------- build dispatch lists: block-aggregated atomics
__global__ __launch_bounds__(256) void build_lists_kernel(
    const int* __restrict__ t2, int* __restrict__ counts, int* __restrict__ ent)
{
    __shared__ int hist[8], base[8];
    const int r = blockIdx.x * 256 + threadIdx.x;
    if (threadIdx.x < 8) hist[threadIdx.x] = 0;
    __syncthreads();
    const int v = t2[r];
    const int i1 = v & 255, i2 = v >> 8;
    const int rk1 = atomicAdd(&hist[i1], 1);
    const int rk2 = atomicAdd(&hist[i2], 1);
    __syncthreads();
    if (threadIdx.x < 8) base[threadIdx.x] = atomicAdd(&counts[threadIdx.x], hist[threadIdx.x]);
    __syncthreads();
    ent[i1 * B_ROWS + base[i1] + rk1] = (r << 1);
    ent[i2 * B_ROWS + base[i2] + rk2] = (r << 1) | 1;
}

// ---------------- sparse fused expert kernel: block = (expert e, tile t) of 32 assigned rows.
// No X staging (read from L2); LDS 50.6 KB -> 3 blocks/CU.
__global__ __launch_bounds__(512, 6) void expert_fused_kernel(
    const ushort* __restrict__ xh,
    const __hip_bfloat16* __restrict__ W1q,
    const __hip_bfloat16* __restrict__ W2q,
    const __hip_bfloat16* __restrict__ W3q,
    const float* __restrict__ s1, const float* __restrict__ s2, const float* __restrict__ s3,
    const float* __restrict__ eb1, const float* __restrict__ eb2, const float* __restrict__ eb3,
    const float* __restrict__ gate,
    const int* __restrict__ counts, const int* __restrict__ ent,
    float* __restrict__ S0, float* __restrict__ S1)
{
    const int e = blockIdx.y, t = blockIdx.x;
    const int cnt = counts[e];
    if (t * 32 >= cnt) return;

    __shared__ __align__(16) __hip_bfloat16 A1s[32][520];
    __shared__ __align__(16) __hip_bfloat16 A2s[32][264];
    __shared__ int rowL[32];
    __shared__ int slotL[32];
    __shared__ float gL[32];

    const int tid = threadIdx.x;
    const int wave = tid >> 6;
    const int lane = tid & 63;
    const int lm = lane & 15;
    const int lk = lane >> 4;

    if (tid < 32) {
        int idx = t * 32 + tid;
        if (idx < cnt) {
            int entv = ent[e * B_ROWS + idx];
            int r = entv >> 1;
            rowL[tid] = r;
            slotL[tid] = entv & 1;
            gL[tid] = gate[(size_t)r * NE + e];
        } else {
            rowL[tid] = -1; slotL[tid] = 0; gL[tid] = 0.f;
        }
    }
    __syncthreads();

    // ---- layer 1: gathered X (32x768) @ W1q_e^T -> A1s (32x512)
    {
        int R0 = rowL[lm];      if (R0 < 0) R0 = 0;
        int R1 = rowL[16 + lm]; if (R1 < 0) R1 = 0;
        const ushort* xr0 = xh + (size_t)R0 * IN_DIM + lk * 8;
        const ushort* xr1 = xh + (size_t)R1 * IN_DIM + lk * 8;
        const ushort* Wb = (const ushort*)W1q + (size_t)e * H1 * IN_DIM + lk * 8;
        const ushort* bp0 = Wb + (size_t)((wave * 4 + 0) * 16 + lm) * IN_DIM;
        const ushort* bp1 = Wb + (size_t)((wave * 4 + 1) * 16 + lm) * IN_DIM;
        const ushort* bp2 = Wb + (size_t)((wave * 4 + 2) * 16 + lm) * IN_DIM;
        const ushort* bp3 = Wb + (size_t)((wave * 4 + 3) * 16 + lm) * IN_DIM;
        const float* bias = eb1 + e * H1;
        const float sc = s1[e];
        f32x4 acc[2][4] = {};
        for (int kk = 0; kk < IN_DIM; kk += 32) {
            bf16x8 a0 = *(const bf16x8*)(xr0 + kk);
            bf16x8 a1 = *(const bf16x8*)(xr1 + kk);
            bf16x8 b0 = *(const bf16x8*)(bp0 + kk);
            bf16x8 b1 = *(const bf16x8*)(bp1 + kk);
            bf16x8 b2 = *(const bf16x8*)(bp2 + kk);
            bf16x8 b3 = *(const bf16x8*)(bp3 + kk);
            acc[0][0] = mfma16(a0, b0, acc[0][0]);
            acc[1][0] = mfma16(a1, b0, acc[1][0]);
            acc[0][1] = mfma16(a0, b1, acc[0][1]);
            acc[1][1] = mfma16(a1, b1, acc[1][1]);
            acc[0][2] = mfma16(a0, b2, acc[0][2]);
            acc[1][2] = mfma16(a1, b2, acc[1][2]);
            acc[0][3] = mfma16(a0, b3, acc[0][3]);
            acc[1][3] = mfma16(a1, b3, acc[1][3]);
        }
        #pragma unroll
        for (int n = 0; n < 4; ++n) {
            int ncol = (wave * 4 + n) * 16 + lm;
            float bv = bias[ncol];
            #pragma unroll
            for (int m = 0; m < 2; ++m)
                #pragma unroll
                for (int r = 0; r < 4; ++r) {
                    float v = fmaf(acc[m][n][r], sc, bv);
                    v = v > 0.f ? v : 0.f;
                    A1s[m * 16 + lk * 4 + r][ncol] = __float2bfloat16(v);
                }
        }
    }
    __syncthreads();

    // ---- layer 2: A1s(32x512) @ W2q_e^T -> A2s(32x256)
    {
        const ushort* Wb = (const ushort*)W2q + (size_t)e * H2 * H1 + lk * 8;
        const ushort* bp0 = Wb + (size_t)((wave * 2 + 0) * 16 + lm) * H1;
        const ushort* bp1 = Wb + (size_t)((wave * 2 + 1) * 16 + lm) * H1;
        const float* bias = eb2 + e * H2;
        const float sc = s2[e];
        f32x4 acc[2][2] = {};
        for (int kk = 0; kk < H1; kk += 32) {
            bf16x8 a0 = *(const bf16x8*)&A1s[lm][kk + lk * 8];
            bf16x8 a1 = *(const bf16x8*)&A1s[16 + lm][kk + lk * 8];
            bf16x8 b0 = *(const bf16x8*)(bp0 + kk);
            bf16x8 b1 = *(const bf16x8*)(bp1 + kk);
            acc[0][0] = mfma16(a0, b0, acc[0][0]);
            acc[1][0] = mfma16(a1, b0, acc[1][0]);
            acc[0][1] = mfma16(a0, b1, acc[0][1]);
            acc[1][1] = mfma16(a1, b1, acc[1][1]);
        }
        #pragma unroll
        for (int n = 0; n < 2; ++n) {
            int ncol = (wave * 2 + n) * 16 + lm;
            float bv = bias[ncol];
            #pragma unroll
            for (int m = 0; m < 2; ++m)
                #pragma unroll
                for (int r = 0; r < 4; ++r) {
                    float v = fmaf(acc[m][n][r], sc, bv);
                    v = v > 0.f ? v : 0.f;
                    A2s[m * 16 + lk * 4 + r][ncol] = __float2bfloat16(v);
                }
        }
    }
    __syncthreads();

    // ---- layer 3: A2s(32x256) @ W3q_e^T(64x256) -> gated write to slot buffer
    {
        const ushort* Wb = (const ushort*)W3q + (size_t)e * NC_PAD * H2 + lk * 8;
        const float* bias = eb3 + e * NC;
        const float sc = s3[e];
        const int mt = wave & 1, nt = wave >> 1;
        const ushort* bp = Wb + (size_t)(nt * 16 + lm) * H2;
        f32x4 acc = {};
        for (int kk = 0; kk < H2; kk += 32) {
            bf16x8 a = *(const bf16x8*)&A2s[mt * 16 + lm][kk + lk * 8];
            bf16x8 b = *(const bf16x8*)(bp + kk);
            acc = mfma16(a, b, acc);
        }
        int col = nt * 16 + lm;
        if (col < NC) {
            float bv = bias[col];
            #pragma unroll
            for (int r = 0; r < 4; ++r) {
                int row = mt * 16 + lk * 4 + r;
                int R = rowL[row];
                if (R >= 0) {
                    float v = gL[row] * fmaf(acc[r], sc, bv);
                    float* Sb = slotL[row] ? S1 : S0;
                    Sb[(size_t)R * 64 + col] = v;
                }
            }
        }
    }
}

// ---------------- combine
__global__ __launch_bounds__(256) void combine_kernel(
    const float* __restrict__ S0, const float* __restrict__ S1, float* __restrict__ out)
{
    int i = blockIdx.x * 256 + threadIdx.x;
    if (i < B_ROWS * NC) {
        int row = i / NC, col = i % NC;
        out[i] = S0[(size_t)row * 64 + col] + S1[(size_t)row * 64 + col];
    }
}

extern "C" void kernel_launch(void* const* d_in, const int* in_sizes, int n_in,
                              void* d_out, int out_size, void* d_ws, size_t ws_size,
                              hipStream_t stream) {
    const float* x   = (const float*)d_in[0];
    const float* rW1 = (const float*)d_in[1];
    const float* rb1 = (const float*)d_in[2];
    const float* rW2 = (const float*)d_in[3];
    const float* rb2 = (const float*)d_in[4];
    const float* rW3 = (const float*)d_in[5];
    const float* rb3 = (const float*)d_in[6];
    const float* eW1 = (const float*)d_in[7];
    const float* eb1 = (const float*)d_in[8];
    const float* eW2 = (const float*)d_in[9];
    const float* eb2 = (const float*)d_in[10];
    const float* eW3 = (const float*)d_in[11];
    const float* eb3 = (const float*)d_in[12];

    float* out_main = (float*)d_out;
    float* router_p = out_main + (size_t)B_ROWS * NC;
    float* lb_out   = router_p + (size_t)B_ROWS * NE;

    char* ws = (char*)d_ws;
    size_t off = 0;
    __hip_bfloat16* W1q = (__hip_bfloat16*)(ws + off); off += (size_t)NE * H1 * IN_DIM * 2;
    __hip_bfloat16* W2q = (__hip_bfloat16*)(ws + off); off += (size_t)NE * H2 * H1 * 2;
    __hip_bfloat16* W3q = (__hip_bfloat16*)(ws + off); off += (size_t)NE * NC_PAD * H2 * 2;
    ushort* xh  = (ushort*)(ws + off); off += (size_t)B_ROWS * IN_DIM * 2;
    ushort* xl  = (ushort*)(ws + off); off += (size_t)B_ROWS * IN_DIM * 2;
    float* S0   = (float*)(ws + off);  off += (size_t)B_ROWS * 64 * 4;
    float* S1   = (float*)(ws + off);  off += (size_t)B_ROWS * 64 * 4;
    ushort* w1h = (ushort*)(ws + off); off += (size_t)RH1 * IN_DIM * 2;
    ushort* w1l = (ushort*)(ws + off); off += (size_t)RH1 * IN_DIM * 2;
    ushort* w2h = (ushort*)(ws + off); off += (size_t)RH2 * RH1 * 2;
    ushort* w2l = (ushort*)(ws + off); off += (size_t)RH2 * RH1 * 2;
    float* gate = (float*)(ws + off);  off += (size_t)B_ROWS * NE * 4;
    int*   ent  = (int*)(ws + off);    off += (size_t)NE * B_ROWS * 4;
    int*   t2   = (int*)(ws + off);    off += (size_t)B_ROWS * 4;
    int* counts = (int*)(ws + off);    off += 256;
    float* s1   = (float*)(ws + off);  off += 256;
    float* s2   = (float*)(ws + off);  off += 256;
    float* s3   = (float*)(ws + off);  off += 256;
    float* p1   = (float*)(ws + off);  off += NE * NBLK_SUM * 4;
    float* p2   = (float*)(ws + off);  off += NE * NBLK_SUM * 4;
    float* p3   = (float*)(ws + off);  off += NE * NBLK_SUM * 4;

    // 1) prep: abs-sums, quantize, hi/lo decompositions, finalize scales (+zero counts)
    absum_all_kernel<<<dim3(NBLK_SUM, 24), 256, 0, stream>>>(eW1, eW2, eW3, p1, p2, p3);
    quant_all_kernel<<<dim3(384, 24), 256, 0, stream>>>(eW1, eW2, eW3, W1q, W2q, W3q);
    decomp_all_kernel<<<3128, 256, 0, stream>>>(x, xh, xl, rW1, w1h, w1l, rW2, w2h, w2l);
    finalize_scales_kernel<<<1, 64, 0, stream>>>(p1, p2, p3, s1, s2, s3, counts);

    // 2) fused router (3 layers + softmax + top-2)
    router_fused_kernel<<<B_ROWS / 32, 512, 0, stream>>>(
        xh, xl, w1h, w1l, rb1, w2h, w2l, rb2, rW3, rb3, router_p, gate, lb_out, t2);
    build_lists_kernel<<<B_ROWS / 256, 256, 0, stream>>>(t2, counts, ent);

    // 3) sparse fused experts (top-2 only) + combine
    expert_fused_kernel<<<dim3(B_ROWS / 32, NE), 512, 0, stream>>>(
        xh, W1q, W2q, W3q, s1, s2, s3, eb1, eb2, eb3, gate, counts, ent, S0, S1);
    combine_kernel<<<(B_ROWS * NC + 255) / 256, 256, 0, stream>>>(S0, S1, out_main);
}

// Round 5
// 317.474 us; speedup vs baseline: 3.6956x; 1.1457x over previous
//
#include <hip/hip_runtime.h>
#include <hip/hip_bf16.h>

typedef __attribute__((ext_vector_type(4))) float f32x4;
typedef __attribute__((ext_vector_type(8))) short bf16x8;

#define B_ROWS 16384
#define IN_DIM 768
#define H1 512
#define H2 256
#define NC 50
#define NC_PAD 64
#define NE 8
#define RH1 256
#define RH2 128
#define NBLK_SUM 32

static __device__ __forceinline__ f32x4 mfma16(bf16x8 a, bf16x8 b, f32x4 c) {
    return __builtin_amdgcn_mfma_f32_16x16x32_bf16(a, b, c, 0, 0, 0);
}

// ---------------- merged abs-sum partial reduce: grid (NBLK_SUM, 24)
__global__ __launch_bounds__(256) void absum_all_kernel(
    const float* __restrict__ eW1, const float* __restrict__ eW2, const float* __restrict__ eW3,
    float* __restrict__ p1, float* __restrict__ p2, float* __restrict__ p3)
{
    const int mat = blockIdx.y >> 3, e = blockIdx.y & 7;
    const float* W; float* P; int n;
    if (mat == 0)      { W = eW1; P = p1; n = H1 * IN_DIM; }
    else if (mat == 1) { W = eW2; P = p2; n = H2 * H1; }
    else               { W = eW3; P = p3; n = NC * H2; }
    const float4* We = (const float4*)(W + (size_t)e * n);
    const int n4 = n >> 2;
    float s = 0.f;
    for (int i = blockIdx.x * 256 + threadIdx.x; i < n4; i += NBLK_SUM * 256) {
        float4 v = We[i];
        s += fabsf(v.x) + fabsf(v.y) + fabsf(v.z) + fabsf(v.w);
    }
    const int lane = threadIdx.x & 63, wave = threadIdx.x >> 6;
    #pragma unroll
    for (int o = 32; o; o >>= 1) s += __shfl_down(s, o);
    __shared__ float red[4];
    if (lane == 0) red[wave] = s;
    __syncthreads();
    if (threadIdx.x == 0)
        P[e * NBLK_SUM + blockIdx.x] = red[0] + red[1] + red[2] + red[3];
}

// ---------------- finalize scales + zero dispatch counts
__global__ __launch_bounds__(64) void finalize_scales_kernel(
    const float* __restrict__ p1, const float* __restrict__ p2, const float* __restrict__ p3,
    float* __restrict__ s1, float* __restrict__ s2, float* __restrict__ s3,
    int* __restrict__ counts)
{
    int t = threadIdx.x;
    if (t < 8) {
        float a = 0.f;
        for (int i = 0; i < NBLK_SUM; ++i) a += p1[t * NBLK_SUM + i];
        s1[t] = a / (float)(H1 * IN_DIM);
    } else if (t < 16) {
        int e = t - 8; float a = 0.f;
        for (int i = 0; i < NBLK_SUM; ++i) a += p2[e * NBLK_SUM + i];
        s2[e] = a / (float)(H2 * H1);
    } else if (t < 24) {
        int e = t - 16; float a = 0.f;
        for (int i = 0; i < NBLK_SUM; ++i) a += p3[e * NBLK_SUM + i];
        s3[e] = a / (float)(NC * H2);
    } else if (t < 32) {
        counts[t - 24] = 0;
    }
}

// ---------------- merged quantize: grid (384, 24)
__global__ __launch_bounds__(256) void quant_all_kernel(
    const float* __restrict__ eW1, const float* __restrict__ eW2, const float* __restrict__ eW3,
    __hip_bfloat16* __restrict__ W1q, __hip_bfloat16* __restrict__ W2q, __hip_bfloat16* __restrict__ W3q)
{
    const int mat = blockIdx.y >> 3, e = blockIdx.y & 7;
    const float* W; __hip_bfloat16* Q; int n, ntot;
    if (mat == 0)      { W = eW1; Q = W1q; n = H1 * IN_DIM; ntot = n; }
    else if (mat == 1) { W = eW2; Q = W2q; n = H2 * H1;     ntot = n; }
    else               { W = eW3; Q = W3q; n = NC * H2;     ntot = NC_PAD * H2; }
    int i4 = (blockIdx.x * 256 + threadIdx.x) * 4;
    if (i4 >= ntot) return;
    const float* We = W + (size_t)e * n;
    __hip_bfloat16* Wo = Q + (size_t)e * ntot;
    ushort o[4];
    #pragma unroll
    for (int j = 0; j < 4; ++j) {
        int i = i4 + j;
        float q = 0.f;
        if (i < n) {
            float w = We[i];
            q = (fabsf(w) > 0.05f) ? (w > 0.f ? 1.f : -1.f) : 0.f;
        }
        __hip_bfloat16 h = __float2bfloat16(q);
        o[j] = *(ushort*)&h;
    }
    *(ushort4*)&Wo[i4] = make_ushort4(o[0], o[1], o[2], o[3]);
}

// ---------------- merged hi/lo decomposition: x (3072 blocks), rW1 (48), rW2 (8)
static __device__ __forceinline__ void decomp4(
    const float4* __restrict__ in, ushort4* __restrict__ hi, ushort4* __restrict__ lo, int i)
{
    float4 v = in[i];
    float vv[4] = {v.x, v.y, v.z, v.w};
    ushort ho[4], lo4[4];
    #pragma unroll
    for (int j = 0; j < 4; ++j) {
        __hip_bfloat16 h = __float2bfloat16(vv[j]);
        float hf = __bfloat162float(h);
        __hip_bfloat16 l = __float2bfloat16(vv[j] - hf);
        ho[j] = *(ushort*)&h; lo4[j] = *(ushort*)&l;
    }
    hi[i] = make_ushort4(ho[0], ho[1], ho[2], ho[3]);
    lo[i] = make_ushort4(lo4[0], lo4[1], lo4[2], lo4[3]);
}

__global__ __launch_bounds__(256) void decomp_all_kernel(
    const float* __restrict__ x, ushort* __restrict__ xh, ushort* __restrict__ xl,
    const float* __restrict__ rW1, ushort* __restrict__ w1h, ushort* __restrict__ w1l,
    const float* __restrict__ rW2, ushort* __restrict__ w2h, ushort* __restrict__ w2l)
{
    const int bx = blockIdx.x;
    const float4* in; ushort4* hi; ushort4* lo; int base;
    if (bx < 3072)      { in = (const float4*)x;   hi = (ushort4*)xh;  lo = (ushort4*)xl;  base = bx * 1024; }
    else if (bx < 3120) { in = (const float4*)rW1; hi = (ushort4*)w1h; lo = (ushort4*)w1l; base = (bx - 3072) * 1024; }
    else                { in = (const float4*)rW2; hi = (ushort4*)w2h; lo = (ushort4*)w2l; base = (bx - 3120) * 1024; }
    #pragma unroll
    for (int j = 0; j < 4; ++j)
        decomp4(in, hi, lo, base + j * 256 + threadIdx.x);
}

// ---------------- fully fused router: x -> h1 -> h2 -> logits/softmax/top2.
__global__ __launch_bounds__(512, 4) void router_fused_kernel(
    const ushort* __restrict__ xh, const ushort* __restrict__ xl,
    const ushort* __restrict__ w1h, const ushort* __restrict__ w1l, const float* __restrict__ rb1,
    const ushort* __restrict__ w2h, const ushort* __restrict__ w2l, const float* __restrict__ rb2,
    const float* __restrict__ rW3, const float* __restrict__ rb3,
    float* __restrict__ router_p, float* __restrict__ gate,
    float* __restrict__ lb_out, int* __restrict__ t2)
{
    __shared__ __align__(16) ushort h1hs[32][264];
    __shared__ __align__(16) ushort h1ls[32][264];
    __shared__ __align__(16) float h2s[32][132];

    const int tid = threadIdx.x, wave = tid >> 6, lane = tid & 63;
    const int lm = lane & 15, lk = lane >> 4;
    const int r0 = blockIdx.x * 32;

    // ---- layer 1: (32 x 768) @ rW1^T(256x768) -> h1 (32x256)
    {
        const ushort* a0h = xh + (size_t)(r0 + lm) * IN_DIM + lk * 8;
        const ushort* a0l = xl + (size_t)(r0 + lm) * IN_DIM + lk * 8;
        const ushort* a1h = xh + (size_t)(r0 + 16 + lm) * IN_DIM + lk * 8;
        const ushort* a1l = xl + (size_t)(r0 + 16 + lm) * IN_DIM + lk * 8;
        const ushort* b0h = w1h + (size_t)(wave * 32 + lm) * IN_DIM + lk * 8;
        const ushort* b0l = w1l + (size_t)(wave * 32 + lm) * IN_DIM + lk * 8;
        const ushort* b1h = w1h + (size_t)(wave * 32 + 16 + lm) * IN_DIM + lk * 8;
        const ushort* b1l = w1l + (size_t)(wave * 32 + 16 + lm) * IN_DIM + lk * 8;
        f32x4 acc[2][2] = {};
        for (int kk = 0; kk < IN_DIM; kk += 32) {
            bf16x8 ah0 = *(const bf16x8*)(a0h + kk), al0 = *(const bf16x8*)(a0l + kk);
            bf16x8 ah1 = *(const bf16x8*)(a1h + kk), al1 = *(const bf16x8*)(a1l + kk);
            bf16x8 bh0 = *(const bf16x8*)(b0h + kk), bl0 = *(const bf16x8*)(b0l + kk);
            bf16x8 bh1 = *(const bf16x8*)(b1h + kk), bl1 = *(const bf16x8*)(b1l + kk);
            acc[0][0] = mfma16(ah0, bh0, acc[0][0]);
            acc[0][0] = mfma16(ah0, bl0, acc[0][0]);
            acc[0][0] = mfma16(al0, bh0, acc[0][0]);
            acc[0][1] = mfma16(ah0, bh1, acc[0][1]);
            acc[0][1] = mfma16(ah0, bl1, acc[0][1]);
            acc[0][1] = mfma16(al0, bh1, acc[0][1]);
            acc[1][0] = mfma16(ah1, bh0, acc[1][0]);
            acc[1][0] = mfma16(ah1, bl0, acc[1][0]);
            acc[1][0] = mfma16(al1, bh0, acc[1][0]);
            acc[1][1] = mfma16(ah1, bh1, acc[1][1]);
            acc[1][1] = mfma16(ah1, bl1, acc[1][1]);
            acc[1][1] = mfma16(al1, bh1, acc[1][1]);
        }
        #pragma unroll
        for (int n = 0; n < 2; ++n) {
            int col = wave * 32 + n * 16 + lm;
            float bv = rb1[col];
            #pragma unroll
            for (int m = 0; m < 2; ++m)
                #pragma unroll
                for (int r = 0; r < 4; ++r) {
                    float v = acc[m][n][r] + bv;
                    v = v > 0.f ? v : 0.f;
                    __hip_bfloat16 h = __float2bfloat16(v);
                    float hf = __bfloat162float(h);
                    __hip_bfloat16 l = __float2bfloat16(v - hf);
                    int row = m * 16 + lk * 4 + r;
                    h1hs[row][col] = *(ushort*)&h;
                    h1ls[row][col] = *(ushort*)&l;
                }
        }
    }
    __syncthreads();

    // ---- layer 2: (32 x 256) @ rW2^T(128x256) -> h2 (32x128)
    {
        const ushort* b2h = w2h + (size_t)(wave * 16 + lm) * RH1 + lk * 8;
        const ushort* b2l = w2l + (size_t)(wave * 16 + lm) * RH1 + lk * 8;
        f32x4 acc2[2] = {};
        for (int kk = 0; kk < RH1; kk += 32) {
            bf16x8 ah0 = *(const bf16x8*)&h1hs[lm][kk + lk * 8];
            bf16x8 al0 = *(const bf16x8*)&h1ls[lm][kk + lk * 8];
            bf16x8 ah1 = *(const bf16x8*)&h1hs[16 + lm][kk + lk * 8];
            bf16x8 al1 = *(const bf16x8*)&h1ls[16 + lm][kk + lk * 8];
            bf16x8 bh = *(const bf16x8*)(b2h + kk);
            bf16x8 bl = *(const bf16x8*)(b2l + kk);
            acc2[0] = mfma16(ah0, bh, acc2[0]);
            acc2[0] = mfma16(ah0, bl, acc2[0]);
            acc2[0] = mfma16(al0, bh, acc2[0]);
            acc2[1] = mfma16(ah1, bh, acc2[1]);
            acc2[1] = mfma16(ah1, bl, acc2[1]);
            acc2[1] = mfma16(al1, bh, acc2[1]);
        }
        int col2 = wave * 16 + lm;
        float bv = rb2[col2];
        #pragma unroll
        for (int m = 0; m < 2; ++m)
            #pragma unroll
            for (int r = 0; r < 4; ++r) {
                float v = acc2[m][r] + bv;
                h2s[m * 16 + lk * 4 + r][col2] = v > 0.f ? v : 0.f;
            }
    }
    __syncthreads();

    // ---- head
    const int o = lane >> 3, kq = lane & 7;
    #pragma unroll
    for (int i = 0; i < 4; ++i) {
        int rloc = wave * 4 + i;
        int b = r0 + rloc;
        float s = 0.f;
        #pragma unroll
        for (int q = 0; q < 4; ++q) {
            float4 hv = *(const float4*)&h2s[rloc][kq * 16 + q * 4];
            float4 wv = *(const float4*)&rW3[o * RH2 + kq * 16 + q * 4];
            s += hv.x * wv.x + hv.y * wv.y + hv.z * wv.z + hv.w * wv.w;
        }
        s += __shfl_xor(s, 1);
        s += __shfl_xor(s, 2);
        s += __shfl_xor(s, 4);
        float logit = s + rb3[o];
        float l[8];
        #pragma unroll
        for (int j = 0; j < 8; ++j) l[j] = __shfl(logit, j * 8);
        float m = l[0];
        #pragma unroll
        for (int j = 1; j < 8; ++j) m = fmaxf(m, l[j]);
        float p[8]; float sum = 0.f;
        #pragma unroll
        for (int j = 0; j < 8; ++j) { p[j] = expf(l[j] - m); sum += p[j]; }
        float inv = 1.f / sum;
        #pragma unroll
        for (int j = 0; j < 8; ++j) p[j] *= inv;
        int i1 = 0; float v1 = p[0];
        #pragma unroll
        for (int j = 1; j < 8; ++j) if (p[j] > v1) { v1 = p[j]; i1 = j; }
        int i2 = -1; float v2 = -1.f;
        #pragma unroll
        for (int j = 0; j < 8; ++j) if (j != i1 && p[j] > v2) { v2 = p[j]; i2 = j; }
        if (lane < 8) {
            router_p[(size_t)b * 8 + lane] = p[lane];
            float g = (lane == i1) ? v1 * 0.5f : ((lane == i2) ? v2 * 0.5f : 0.f);
            gate[(size_t)b * 8 + lane] = g;
        }
        if (lane == 0) t2[b] = i1 | (i2 << 8);
    }
    if (blockIdx.x == 0 && tid == 0) lb_out[0] = 0.f;
}

// ---------------- build dispatch lists
__global__ __launch_bounds__(256) void build_lists_kernel(
    const int* __restrict__ t2, int* __restrict__ counts, int* __restrict__ ent)
{
    __shared__ int hist[8], base[8];
    const int r = blockIdx.x * 256 + threadIdx.x;
    if (threadIdx.x < 8) hist[threadIdx.x] = 0;
    __syncthreads();
    const int v = t2[r];
    const int i1 = v & 255, i2 = v >> 8;
    const int rk1 = atomicAdd(&hist[i1], 1);
    const int rk2 = atomicAdd(&hist[i2], 1);
    __syncthreads();
    if (threadIdx.x < 8) base[threadIdx.x] = atomicAdd(&counts[threadIdx.x], hist[threadIdx.x]);
    __syncthreads();
    ent[i1 * B_ROWS + base[i1] + rk1] = (r << 1);
    ent[i2 * B_ROWS + base[i2] + rk2] = (r << 1) | 1;
}

// ---------------- sparse fused expert kernel.
// X staged in double-buffered 128-K chunks; A2s aliases the chunk region.
// LDS = 33280 (A1s) + 17408 (Xd | A2s) = 50688 B -> 3 blocks/CU.
#define CHK 128
#define NCHK (IN_DIM / CHK)
__global__ __launch_bounds__(512) void expert_fused_kernel(
    const ushort* __restrict__ xh,
    const __hip_bfloat16* __restrict__ W1q,
    const __hip_bfloat16* __restrict__ W2q,
    const __hip_bfloat16* __restrict__ W3q,
    const float* __restrict__ s1, const float* __restrict__ s2, const float* __restrict__ s3,
    const float* __restrict__ eb1, const float* __restrict__ eb2, const float* __restrict__ eb3,
    const float* __restrict__ gate,
    const int* __restrict__ counts, const int* __restrict__ ent,
    float* __restrict__ S0, float* __restrict__ S1)
{
    const int e = blockIdx.y, t = blockIdx.x;
    const int cnt = counts[e];
    if (t * 32 >= cnt) return;

    __shared__ __align__(16) unsigned char smem[33280 + 17408];
    __hip_bfloat16 (*A1s)[520] = (__hip_bfloat16(*)[520])smem;
    ushort (*Xd)[32][136]      = (ushort(*)[32][136])(smem + 33280);
    __hip_bfloat16 (*A2s)[264] = (__hip_bfloat16(*)[264])(smem + 33280);
    __shared__ int rowL[32];
    __shared__ int slotL[32];
    __shared__ float gL[32];

    const int tid = threadIdx.x;
    const int wave = tid >> 6;
    const int lane = tid & 63;
    const int lm = lane & 15;
    const int lk = lane >> 4;

    if (tid < 32) {
        int idx = t * 32 + tid;
        if (idx < cnt) {
            int entv = ent[e * B_ROWS + idx];
            int r = entv >> 1;
            rowL[tid] = r;
            slotL[tid] = entv & 1;
            gL[tid] = gate[(size_t)r * NE + e];
        } else {
            rowL[tid] = -1; slotL[tid] = 0; gL[tid] = 0.f;
        }
    }
    __syncthreads();

    // staging geometry: 512 threads x 16B = 8 KB = one 32x128 bf16 chunk
    const int srow = tid >> 4;          // 0..31
    const int sc8  = (tid & 15) * 8;    // 0,8,...,120
    int SR = rowL[srow]; if (SR < 0) SR = 0;
    const ushort* sg = xh + (size_t)SR * IN_DIM + sc8;

    // stage chunk 0
    *(bf16x8*)&Xd[0][srow][sc8] = *(const bf16x8*)sg;
    __syncthreads();

    // ---- layer 1: X(32x768, chunked) @ W1q_e^T(512x768) -> A1s (32x512)
    {
        const ushort* Wb = (const ushort*)W1q + (size_t)e * H1 * IN_DIM + lk * 8;
        const ushort* bp0 = Wb + (size_t)((wave * 4 + 0) * 16 + lm) * IN_DIM;
        const ushort* bp1 = Wb + (size_t)((wave * 4 + 1) * 16 + lm) * IN_DIM;
        const ushort* bp2 = Wb + (size_t)((wave * 4 + 2) * 16 + lm) * IN_DIM;
        const ushort* bp3 = Wb + (size_t)((wave * 4 + 3) * 16 + lm) * IN_DIM;
        f32x4 acc[2][4] = {};
        for (int cc = 0; cc < NCHK; ++cc) {
            bf16x8 sv;
            if (cc + 1 < NCHK) sv = *(const bf16x8*)(sg + (cc + 1) * CHK);  // issue-early
            const ushort (*Xc)[136] = Xd[cc & 1];
            #pragma unroll
            for (int k2 = 0; k2 < CHK / 32; ++k2) {
                const int kk = k2 * 32;
                const int kg = cc * CHK + kk;
                bf16x8 a0 = *(const bf16x8*)&Xc[lm][kk + lk * 8];
                bf16x8 a1 = *(const bf16x8*)&Xc[16 + lm][kk + lk * 8];
                bf16x8 b0 = *(const bf16x8*)(bp0 + kg);
                bf16x8 b1 = *(const bf16x8*)(bp1 + kg);
                bf16x8 b2 = *(const bf16x8*)(bp2 + kg);
                bf16x8 b3 = *(const bf16x8*)(bp3 + kg);
                acc[0][0] = mfma16(a0, b0, acc[0][0]);
                acc[1][0] = mfma16(a1, b0, acc[1][0]);
                acc[0][1] = mfma16(a0, b1, acc[0][1]);
                acc[1][1] = mfma16(a1, b1, acc[1][1]);
                acc[0][2] = mfma16(a0, b2, acc[0][2]);
                acc[1][2] = mfma16(a1, b2, acc[1][2]);
                acc[0][3] = mfma16(a0, b3, acc[0][3]);
                acc[1][3] = mfma16(a1, b3, acc[1][3]);
            }
            if (cc + 1 < NCHK) *(bf16x8*)&Xd[(cc + 1) & 1][srow][sc8] = sv;  // write-late
            __syncthreads();
        }
        const float* bias = eb1 + e * H1;
        const float sc = s1[e];
        #pragma unroll
        for (int n = 0; n < 4; ++n) {
            int ncol = (wave * 4 + n) * 16 + lm;
            float bv = bias[ncol];
            #pragma unroll
            for (int m = 0; m < 2; ++m)
                #pragma unroll
                for (int r = 0; r < 4; ++r) {
                    float v = fmaf(acc[m][n][r], sc, bv);
                    v = v > 0.f ? v : 0.f;
                    A1s[m * 16 + lk * 4 + r][ncol] = __float2bfloat16(v);
                }
        }
    }
    __syncthreads();

    // ---- layer 2: A1s(32x512) @ W2q_e^T -> A2s(32x256)  (A2s aliases dead Xd)
    {
        const ushort* Wb = (const ushort*)W2q + (size_t)e * H2 * H1 + lk * 8;
        const ushort* bp0 = Wb + (size_t)((wave * 2 + 0) * 16 + lm) * H1;
        const ushort* bp1 = Wb + (size_t)((wave * 2 + 1) * 16 + lm) * H1;
        const float* bias = eb2 + e * H2;
        const float sc = s2[e];
        f32x4 acc[2][2] = {};
        for (int kk = 0; kk < H1; kk += 32) {
            bf16x8 a0 = *(const bf16x8*)&A1s[lm][kk + lk * 8];
            bf16x8 a1 = *(const bf16x8*)&A1s[16 + lm][kk + lk * 8];
            bf16x8 b0 = *(const bf16x8*)(bp0 + kk);
            bf16x8 b1 = *(const bf16x8*)(bp1 + kk);
            acc[0][0] = mfma16(a0, b0, acc[0][0]);
            acc[1][0] = mfma16(a1, b0, acc[1][0]);
            acc[0][1] = mfma16(a0, b1, acc[0][1]);
            acc[1][1] = mfma16(a1, b1, acc[1][1]);
        }
        #pragma unroll
        for (int n = 0; n < 2; ++n) {
            int ncol = (wave * 2 + n) * 16 + lm;
            float bv = bias[ncol];
            #pragma unroll
            for (int m = 0; m < 2; ++m)
                #pragma unroll
                for (int r = 0; r < 4; ++r) {
                    float v = fmaf(acc[m][n][r], sc, bv);
                    v = v > 0.f ? v : 0.f;
                    A2s[m * 16 + lk * 4 + r][ncol] = __float2bfloat16(v);
                }
        }
    }
    __syncthreads();

    // ---- layer 3: A2s(32x256) @ W3q_e^T(64x256) -> gated write to slot buffer
    {
        const ushort* Wb = (const ushort*)W3q + (size_t)e * NC_PAD * H2 + lk * 8;
        const float* bias = eb3 + e * NC;
        const float sc = s3[e];
        const int mt = wave & 1, nt = wave >> 1;
        const ushort* bp = Wb + (size_t)(nt * 16 + lm) * H2;
        f32x4 acc = {};
        for (int kk = 0; kk < H2; kk += 32) {
            bf16x8 a = *(const bf16x8*)&A2s[mt * 16 + lm][kk + lk * 8];
            bf16x8 b = *(const bf16x8*)(bp + kk);
            acc = mfma16(a, b, acc);
        }
        int col = nt * 16 + lm;
        if (col < NC) {
            float bv = bias[col];
            #pragma unroll
            for (int r = 0; r < 4; ++r) {
                int row = mt * 16 + lk * 4 + r;
                int R = rowL[row];
                if (R >= 0) {
                    float v = gL[row] * fmaf(acc[r], sc, bv);
                    float* Sb = slotL[row] ? S1 : S0;
                    Sb[(size_t)R * 64 + col] = v;
                }
            }
        }
    }
}

// ---------------- combine
__global__ __launch_bounds__(256) void combine_kernel(
    const float* __restrict__ S0, const float* __restrict__ S1, float* __restrict__ out)
{
    int i = blockIdx.x * 256 + threadIdx.x;
    if (i < B_ROWS * NC) {
        int row = i / NC, col = i % NC;
        out[i] = S0[(size_t)row * 64 + col] + S1[(size_t)row * 64 + col];
    }
}

extern "C" void kernel_launch(void* const* d_in, const int* in_sizes, int n_in,
                              void* d_out, int out_size, void* d_ws, size_t ws_size,
                              hipStream_t stream) {
    const float* x   = (const float*)d_in[0];
    const float* rW1 = (const float*)d_in[1];
    const float* rb1 = (const float*)d_in[2];
    const float* rW2 = (const float*)d_in[3];
    const float* rb2 = (const float*)d_in[4];
    const float* rW3 = (const float*)d_in[5];
    const float* rb3 = (const float*)d_in[6];
    const float* eW1 = (const float*)d_in[7];
    const float* eb1 = (const float*)d_in[8];
    const float* eW2 = (const float*)d_in[9];
    const float* eb2 = (const float*)d_in[10];
    const float* eW3 = (const float*)d_in[11];
    const float* eb3 = (const float*)d_in[12];

    float* out_main = (float*)d_out;
    float* router_p = out_main + (size_t)B_ROWS * NC;
    float* lb_out   = router_p + (size_t)B_ROWS * NE;

    char* ws = (char*)d_ws;
    size_t off = 0;
    __hip_bfloat16* W1q = (__hip_bfloat16*)(ws + off); off += (size_t)NE * H1 * IN_DIM * 2;
    __hip_bfloat16* W2q = (__hip_bfloat16*)(ws + off); off += (size_t)NE * H2 * H1 * 2;
    __hip_bfloat16* W3q = (__hip_bfloat16*)(ws + off); off += (size_t)NE * NC_PAD * H2 * 2;
    ushort* xh  = (ushort*)(ws + off); off += (size_t)B_ROWS * IN_DIM * 2;
    ushort* xl  = (ushort*)(ws + off); off += (size_t)B_ROWS * IN_DIM * 2;
    float* S0   = (float*)(ws + off);  off += (size_t)B_ROWS * 64 * 4;
    float* S1   = (float*)(ws + off);  off += (size_t)B_ROWS * 64 * 4;
    ushort* w1h = (ushort*)(ws + off); off += (size_t)RH1 * IN_DIM * 2;
    ushort* w1l = (ushort*)(ws + off); off += (size_t)RH1 * IN_DIM * 2;
    ushort* w2h = (ushort*)(ws + off); off += (size_t)RH2 * RH1 * 2;
    ushort* w2l = (ushort*)(ws + off); off += (size_t)RH2 * RH1 * 2;
    float* gate = (float*)(ws + off);  off += (size_t)B_ROWS * NE * 4;
    int*   ent  = (int*)(ws + off);    off += (size_t)NE * B_ROWS * 4;
    int*   t2   = (int*)(ws + off);    off += (size_t)B_ROWS * 4;
    int* counts = (int*)(ws + off);    off += 256;
    float* s1   = (float*)(ws + off);  off += 256;
    float* s2   = (float*)(ws + off);  off += 256;
    float* s3   = (float*)(ws + off);  off += 256;
    float* p1   = (float*)(ws + off);  off += NE * NBLK_SUM * 4;
    float* p2   = (float*)(ws + off);  off += NE * NBLK_SUM * 4;
    float* p3   = (float*)(ws + off);  off += NE * NBLK_SUM * 4;

    // 1) prep
    absum_all_kernel<<<dim3(NBLK_SUM, 24), 256, 0, stream>>>(eW1, eW2, eW3, p1, p2, p3);
    quant_all_kernel<<<dim3(384, 24), 256, 0, stream>>>(eW1, eW2, eW3, W1q, W2q, W3q);
    decomp_all_kernel<<<3128, 256, 0, stream>>>(x, xh, xl, rW1, w1h, w1l, rW2, w2h, w2l);
    finalize_scales_kernel<<<1, 64, 0, stream>>>(p1, p2, p3, s1, s2, s3, counts);

    // 2) fused router
    router_fused_kernel<<<B_ROWS / 32, 512, 0, stream>>>(
        xh, xl, w1h, w1l, rb1, w2h, w2l, rb2, rW3, rb3, router_p, gate, lb_out, t2);
    build_lists_kernel<<<B_ROWS / 256, 256, 0, stream>>>(t2, counts, ent);

    // 3) sparse fused experts + combine
    expert_fused_kernel<<<dim3(B_ROWS / 32, NE), 512, 0, stream>>>(
        xh, W1q, W2q, W3q, s1, s2, s3, eb1, eb2, eb3, gate, counts, ent, S0, S1);
    combine_kernel<<<(B_ROWS * NC + 255) / 256, 256, 0, stream>>>(S0, S1, out_main);
}